// Round 1
// baseline (2480.253 us; speedup 1.0000x reference)
//
#include <hip/hip_runtime.h>
#include <math.h>

#define B_ 8
#define D_ 60
#define N_ 1024
#define K_ 20
#define P1_ 8192      // B*N
#define P2_ 163840    // B*N*K

// ---- workspace layout (bytes) ----
#define OFF_IDX 0ull                         // int[P2]            = 655360
#define OFF_XX  (655360ull)                  // float[P1]          = 32768
#define OFF_AB  (OFF_XX + 32768ull)          // A/B per layer      <= 16384
#define OFF_S4  (OFF_AB + 16384ull)          // conv4 sum/ssq      <= 4096
#define OFF_H1  (OFF_S4 + 4096ull)           // float[64*P2]       = 41943040
#define OFF_H2  (OFF_H1 + 41943040ull)       // float[64*P2]
#define OFF_H3  (OFF_H2 + 41943040ull)       // float[128*P2]      = 83886080
#define OFF_XC  (OFF_H3 + 83886080ull)       // float[512*P1]      = 16777216
#define OFF_H5  (OFF_XC + 16777216ull)       // float[256*P1]      = 8388608
#define OFF_H6  (OFF_H5 + 8388608ull)        // float[1024*P1]     = 33554432
// total ~216.7 MiB

// ---------------- xx[bn] = sum_d x^2 ----------------
__global__ __launch_bounds__(256) void k_xx(const float* __restrict__ x,
                                            float* __restrict__ xx) {
  int bn = blockIdx.x * 256 + threadIdx.x;
  int b = bn >> 10, n = bn & 1023;
  const float* xb = x + (size_t)b * D_ * N_ + n;
  float s = 0.f;
  for (int d = 0; d < D_; ++d) { float v = xb[(size_t)d * N_]; s += v * v; }
  xx[bn] = s;
}

// ---------------- kNN: one block per (b,n) ----------------
__global__ __launch_bounds__(256) void k_knn(const float* __restrict__ x,
                                             const float* __restrict__ xx,
                                             int* __restrict__ idxb) {
  __shared__ float xn[D_];
  __shared__ float pd[N_];
  __shared__ float wv[4];
  __shared__ int   wi[4];
  int bn = blockIdx.x;
  int b = bn >> 10, n = bn & 1023;
  int tid = threadIdx.x;
  const float* xb = x + (size_t)b * D_ * N_;
  if (tid < D_) xn[tid] = xb[(size_t)tid * N_ + n];
  __syncthreads();
  float xnsq = xx[bn];
  int bbase = bn & ~1023;
  for (int i = 0; i < 4; ++i) {
    int m = tid + i * 256;
    float dot = 0.f;
    for (int d = 0; d < D_; ++d) dot += xn[d] * xb[(size_t)d * N_ + m];
    pd[m] = 2.f * dot - xnsq - xx[bbase + m];   // = -||xn - xm||^2
  }
  __syncthreads();
  for (int kk = 0; kk < K_; ++kk) {
    float bv = -INFINITY; int bi = N_;
    for (int i = 0; i < 4; ++i) {
      int m = tid + i * 256;
      float v = pd[m];
      if (v > bv || (v == bv && m < bi)) { bv = v; bi = m; }
    }
    #pragma unroll
    for (int off = 32; off >= 1; off >>= 1) {
      float ov = __shfl_xor(bv, off);
      int   oi = __shfl_xor(bi, off);
      if (ov > bv || (ov == bv && oi < bi)) { bv = ov; bi = oi; }
    }
    if ((tid & 63) == 0) { wv[tid >> 6] = bv; wi[tid >> 6] = bi; }
    __syncthreads();
    if (tid == 0) {
      float fv = wv[0]; int fi = wi[0];
      for (int q = 1; q < 4; ++q)
        if (wv[q] > fv || (wv[q] == fv && wi[q] < fi)) { fv = wv[q]; fi = wi[q]; }
      idxb[(size_t)bn * K_ + kk] = fi;
      pd[fi] = -INFINITY;
    }
    __syncthreads();
  }
}

// ---------------- conv1: feature built on the fly (Cin=120 -> 64) ----------------
__global__ __launch_bounds__(256) void k_conv1(const float* __restrict__ x,
                                               const int* __restrict__ idxb,
                                               const float* __restrict__ w,
                                               const float* __restrict__ bias,
                                               float* __restrict__ h) {
  int p = blockIdx.x * 256 + threadIdx.x;
  int bn = p / K_;
  int b = bn >> 10, n = bn & 1023;
  int nbr = idxb[p];
  const float* xb = x + (size_t)b * D_ * N_;
  float acc[64];
  #pragma unroll
  for (int o = 0; o < 64; ++o) acc[o] = bias[o];
  for (int c = 0; c < D_; ++c) {
    float ctr = xb[(size_t)c * N_ + n];
    float dif = xb[(size_t)c * N_ + nbr] - ctr;
    #pragma unroll
    for (int o = 0; o < 64; ++o)
      acc[o] += w[o * 120 + c] * dif + w[o * 120 + 60 + c] * ctr;
  }
  #pragma unroll
  for (int o = 0; o < 64; ++o) h[(size_t)o * P2_ + p] = acc[o];
}

// ---------------- generic conv over [Cin][P] -> [Cout][P], 64-ch chunks ----------------
template <int CIN>
__global__ __launch_bounds__(256) void k_conv_std(const float* __restrict__ in,
                                                  const float* __restrict__ w,
                                                  const float* __restrict__ bias,
                                                  float* __restrict__ h, int P) {
  int p = blockIdx.x * 256 + threadIdx.x;
  int ob = blockIdx.y * 64;
  float acc[64];
  #pragma unroll
  for (int o = 0; o < 64; ++o) acc[o] = bias[ob + o];
  for (int c = 0; c < CIN; ++c) {
    float f = in[(size_t)c * P + p];
    #pragma unroll
    for (int o = 0; o < 64; ++o) acc[o] += w[(size_t)(ob + o) * CIN + c] * f;
  }
  #pragma unroll
  for (int o = 0; o < 64; ++o) h[(size_t)(ob + o) * P + p] = acc[o];
}

// ---------------- BN stats over one channel row -> A,B ----------------
__global__ __launch_bounds__(256) void k_stats(const float* __restrict__ h, int P,
                                               const float* __restrict__ g,
                                               const float* __restrict__ be,
                                               float* __restrict__ A,
                                               float* __restrict__ Bp) {
  int o = blockIdx.x;
  const float* row = h + (size_t)o * P;
  float s = 0.f, ss = 0.f;
  for (int i = threadIdx.x; i < P; i += 256) { float v = row[i]; s += v; ss += v * v; }
  __shared__ float rs[256], rss[256];
  rs[threadIdx.x] = s; rss[threadIdx.x] = ss;
  __syncthreads();
  for (int st = 128; st > 0; st >>= 1) {
    if (threadIdx.x < st) { rs[threadIdx.x] += rs[threadIdx.x + st]; rss[threadIdx.x] += rss[threadIdx.x + st]; }
    __syncthreads();
  }
  if (threadIdx.x == 0) {
    float m = rs[0] / P;
    float v = rss[0] / P - m * m;
    float a = g[o] / sqrtf(v + 1e-5f);
    A[o] = a; Bp[o] = be[o] - m * a;
  }
}

// ---------------- BN+lrelu in place + max over k -> xcat row ----------------
__global__ __launch_bounds__(256) void k_apply_max(float* __restrict__ h,
                                                   const float* __restrict__ A,
                                                   const float* __restrict__ Bp,
                                                   float* __restrict__ xrow) {
  int t = blockIdx.x * 256 + threadIdx.x;
  int o = t >> 13;          // P1_ = 8192
  int bn = t & (P1_ - 1);
  float a = A[o], bp = Bp[o];
  float mx = -INFINITY;
  size_t base = (size_t)o * P2_ + (size_t)bn * K_;
  #pragma unroll
  for (int j = 0; j < K_; ++j) {
    float v = h[base + j] * a + bp;
    v = v >= 0.f ? v : 0.2f * v;
    h[base + j] = v;
    mx = fmaxf(mx, v);
  }
  xrow[(size_t)o * P1_ + bn] = mx;
}

// ---------------- BN+lrelu in place (1d layers, P=P1) ----------------
__global__ __launch_bounds__(256) void k_apply_elem(float* __restrict__ h,
                                                    const float* __restrict__ A,
                                                    const float* __restrict__ Bp) {
  int t = blockIdx.x * 256 + threadIdx.x;
  int o = t >> 13;
  float v = h[t] * A[o] + Bp[o];
  h[t] = v >= 0.f ? v : 0.2f * v;
}

// ---------------- conv4 pass 1: stats only (128 -> 256) ----------------
__global__ __launch_bounds__(256) void k_conv4_stats(const float* __restrict__ in,
                                                     const float* __restrict__ w,
                                                     const float* __restrict__ bias,
                                                     float* __restrict__ sum,
                                                     float* __restrict__ ssq) {
  int tid = threadIdx.x;
  int p = blockIdx.x * 256 + tid;
  int ob = blockIdx.y * 64;
  float acc[64];
  #pragma unroll
  for (int o = 0; o < 64; ++o) acc[o] = bias[ob + o];
  for (int c = 0; c < 128; ++c) {
    float f = in[(size_t)c * P2_ + p];
    #pragma unroll
    for (int o = 0; o < 64; ++o) acc[o] += w[(ob + o) * 128 + c] * f;
  }
  __shared__ float lds[32 * 257];
  for (int r = 0; r < 2; ++r) {
    #pragma unroll
    for (int oo = 0; oo < 32; ++oo) lds[oo * 257 + tid] = acc[r * 32 + oo];
    __syncthreads();
    int oo = tid >> 3, seg = tid & 7;
    float s = 0.f, ss = 0.f;
    for (int q = 0; q < 32; ++q) { float v = lds[oo * 257 + seg * 32 + q]; s += v; ss += v * v; }
    #pragma unroll
    for (int off = 1; off < 8; off <<= 1) { s += __shfl_xor(s, off); ss += __shfl_xor(ss, off); }
    if (seg == 0) { atomicAdd(&sum[ob + r * 32 + oo], s); atomicAdd(&ssq[ob + r * 32 + oo], ss); }
    __syncthreads();
  }
}

__global__ __launch_bounds__(256) void k_finalize4(const float* __restrict__ sum,
                                                   const float* __restrict__ ssq,
                                                   const float* __restrict__ g,
                                                   const float* __restrict__ be,
                                                   float* __restrict__ A,
                                                   float* __restrict__ Bp) {
  int o = threadIdx.x;  // 256 channels, 1 block
  float m = sum[o] / (float)P2_;
  float v = ssq[o] / (float)P2_ - m * m;
  float a = g[o] / sqrtf(v + 1e-5f);
  A[o] = a; Bp[o] = be[o] - m * a;
}

__global__ __launch_bounds__(256) void k_x4init(unsigned* __restrict__ xi) {
  xi[(size_t)blockIdx.x * 256 + threadIdx.x] = 0x007FFFFFu;  // encode(-inf)
}

// ---------------- conv4 pass 2: conv + BN + lrelu + max-over-k (no h4 tensor) ----------------
__global__ __launch_bounds__(256) void k_conv4_final(const float* __restrict__ in,
                                                     const float* __restrict__ w,
                                                     const float* __restrict__ bias,
                                                     const float* __restrict__ A,
                                                     const float* __restrict__ Bp,
                                                     unsigned* __restrict__ x4i) {
  int tid = threadIdx.x;
  int p0 = blockIdx.x * 256;
  int p = p0 + tid;
  int ob = blockIdx.y * 64;
  float acc[64];
  #pragma unroll
  for (int o = 0; o < 64; ++o) acc[o] = bias[ob + o];
  for (int c = 0; c < 128; ++c) {
    float f = in[(size_t)c * P2_ + p];
    #pragma unroll
    for (int o = 0; o < 64; ++o) acc[o] += w[(ob + o) * 128 + c] * f;
  }
  #pragma unroll
  for (int o = 0; o < 64; ++o) {
    float v = acc[o] * A[ob + o] + Bp[ob + o];
    acc[o] = v >= 0.f ? v : 0.2f * v;
  }
  __shared__ float lds[32 * 257];
  int g0 = p0 / K_;
  int g1 = (p0 + 255) / K_;
  int ng = g1 - g0 + 1;
  for (int r = 0; r < 2; ++r) {
    #pragma unroll
    for (int oo = 0; oo < 32; ++oo) lds[oo * 257 + tid] = acc[r * 32 + oo];
    __syncthreads();
    int pairs = 32 * ng;
    for (int t = tid; t < pairs; t += 256) {
      int oo = t / ng;
      int gi = t - oo * ng;
      int gg = g0 + gi;
      int ps = max(gg * K_, p0), pe = min(gg * K_ + K_, p0 + 256);
      float m = -INFINITY;
      for (int q = ps; q < pe; ++q) m = fmaxf(m, lds[oo * 257 + (q - p0)]);
      unsigned u = __float_as_uint(m);
      u = (u & 0x80000000u) ? ~u : (u | 0x80000000u);  // order-preserving encode
      int og = ob + r * 32 + oo;
      unsigned* dst = &x4i[(size_t)og * P1_ + gg];
      if (gg * K_ >= p0 && gg * K_ + K_ <= p0 + 256) *dst = u;       // group fully owned
      else atomicMax(dst, u);                                        // straddles blocks
    }
    __syncthreads();
  }
}

__global__ __launch_bounds__(256) void k_x4convert(unsigned* __restrict__ xi) {
  size_t t = (size_t)blockIdx.x * 256 + threadIdx.x;
  unsigned u = xi[t];
  u = (u & 0x80000000u) ? (u & 0x7FFFFFFFu) : ~u;
  ((float*)xi)[t] = __uint_as_float(u);
}

// ---------------- final BN+lrelu + transpose to (B,N,1024) ----------------
__global__ __launch_bounds__(1024) void k_apply6_t(const float* __restrict__ h,
                                                   const float* __restrict__ A,
                                                   const float* __restrict__ Bp,
                                                   float* __restrict__ out) {
  __shared__ float tile[32][33];
  int bx = blockIdx.x;  // bn tiles (256)
  int by = blockIdx.y;  // o tiles (32)
  int tx = threadIdx.x, ty = threadIdx.y;
  int o = by * 32 + ty, bn = bx * 32 + tx;
  float v = h[(size_t)o * P1_ + bn];
  v = v * A[o] + Bp[o];
  v = v >= 0.f ? v : 0.2f * v;
  tile[ty][tx] = v;
  __syncthreads();
  out[(size_t)(bx * 32 + ty) * 1024 + by * 32 + tx] = tile[tx][ty];
}

extern "C" void kernel_launch(void* const* d_in, const int* in_sizes, int n_in,
                              void* d_out, int out_size, void* d_ws, size_t ws_size,
                              hipStream_t stream) {
  const float* x   = (const float*)d_in[0];
  const float* w1  = (const float*)d_in[1];
  const float* b1  = (const float*)d_in[2];
  const float* g1  = (const float*)d_in[3];
  const float* be1 = (const float*)d_in[4];
  const float* w2  = (const float*)d_in[5];
  const float* b2  = (const float*)d_in[6];
  const float* g2  = (const float*)d_in[7];
  const float* be2 = (const float*)d_in[8];
  const float* w3  = (const float*)d_in[9];
  const float* b3  = (const float*)d_in[10];
  const float* g3  = (const float*)d_in[11];
  const float* be3 = (const float*)d_in[12];
  const float* w4  = (const float*)d_in[13];
  const float* b4  = (const float*)d_in[14];
  const float* g4  = (const float*)d_in[15];
  const float* be4 = (const float*)d_in[16];
  const float* w5  = (const float*)d_in[17];
  const float* b5  = (const float*)d_in[18];
  const float* g5  = (const float*)d_in[19];
  const float* be5 = (const float*)d_in[20];
  const float* w6  = (const float*)d_in[21];
  const float* b6  = (const float*)d_in[22];
  const float* g6  = (const float*)d_in[23];
  const float* be6 = (const float*)d_in[24];
  float* out = (float*)d_out;
  char* ws = (char*)d_ws;

  int*   idxb = (int*)(ws + OFF_IDX);
  float* xx   = (float*)(ws + OFF_XX);
  float* ab   = (float*)(ws + OFF_AB);
  float *A1 = ab,        *B1 = ab + 64;
  float *A2 = ab + 128,  *B2 = ab + 192;
  float *A3 = ab + 256,  *B3 = ab + 384;
  float *A4 = ab + 512,  *B4 = ab + 768;
  float *A5 = ab + 1024, *B5 = ab + 1280;
  float *A6 = ab + 1536, *B6 = ab + 2560;
  float* sum4 = (float*)(ws + OFF_S4);
  float* ssq4 = sum4 + 256;
  float* h1   = (float*)(ws + OFF_H1);
  float* h2   = (float*)(ws + OFF_H2);
  float* h3   = (float*)(ws + OFF_H3);
  float* xcat = (float*)(ws + OFF_XC);
  float* h5   = (float*)(ws + OFF_H5);
  float* h6   = (float*)(ws + OFF_H6);

  hipMemsetAsync(sum4, 0, 2048, stream);

  k_xx <<<P1_ / 256, 256, 0, stream>>>(x, xx);
  k_knn<<<P1_, 256, 0, stream>>>(x, xx, idxb);

  // layer 1 (120 -> 64)
  k_conv1<<<P2_ / 256, 256, 0, stream>>>(x, idxb, w1, b1, h1);
  k_stats<<<64, 256, 0, stream>>>(h1, P2_, g1, be1, A1, B1);
  k_apply_max<<<64 * P1_ / 256, 256, 0, stream>>>(h1, A1, B1, xcat);

  // layer 2 (64 -> 64)
  k_conv_std<64><<<dim3(P2_ / 256, 1), 256, 0, stream>>>(h1, w2, b2, h2, P2_);
  k_stats<<<64, 256, 0, stream>>>(h2, P2_, g2, be2, A2, B2);
  k_apply_max<<<64 * P1_ / 256, 256, 0, stream>>>(h2, A2, B2, xcat + (size_t)64 * P1_);

  // layer 3 (64 -> 128)
  k_conv_std<64><<<dim3(P2_ / 256, 2), 256, 0, stream>>>(h2, w3, b3, h3, P2_);
  k_stats<<<128, 256, 0, stream>>>(h3, P2_, g3, be3, A3, B3);
  k_apply_max<<<128 * P1_ / 256, 256, 0, stream>>>(h3, A3, B3, xcat + (size_t)128 * P1_);

  // layer 4 (128 -> 256), h4 never materialized
  k_conv4_stats<<<dim3(P2_ / 256, 4), 256, 0, stream>>>(h3, w4, b4, sum4, ssq4);
  k_finalize4<<<1, 256, 0, stream>>>(sum4, ssq4, g4, be4, A4, B4);
  unsigned* x4i = (unsigned*)(xcat + (size_t)256 * P1_);
  k_x4init<<<256 * P1_ / 256, 256, 0, stream>>>(x4i);
  k_conv4_final<<<dim3(P2_ / 256, 4), 256, 0, stream>>>(h3, w4, b4, A4, B4, x4i);
  k_x4convert<<<256 * P1_ / 256, 256, 0, stream>>>(x4i);

  // layer 5 (512 -> 256) on concat
  k_conv_std<512><<<dim3(P1_ / 256, 4), 256, 0, stream>>>(xcat, w5, b5, h5, P1_);
  k_stats<<<256, 256, 0, stream>>>(h5, P1_, g5, be5, A5, B5);
  k_apply_elem<<<256 * P1_ / 256, 256, 0, stream>>>(h5, A5, B5);

  // layer 6 (256 -> 1024)
  k_conv_std<256><<<dim3(P1_ / 256, 16), 256, 0, stream>>>(h5, w6, b6, h6, P1_);
  k_stats<<<1024, 256, 0, stream>>>(h6, P1_, g6, be6, A6, B6);
  k_apply6_t<<<dim3(P1_ / 32, 1024 / 32), dim3(32, 32), 0, stream>>>(h6, A6, B6, out);

  (void)in_sizes; (void)n_in; (void)out_size; (void)ws_size;
}

// Round 2
// 819.582 us; speedup vs baseline: 3.0262x; 3.0262x over previous
//
#include <hip/hip_runtime.h>
#include <hip/hip_bf16.h>
#include <math.h>

#define B_ 8
#define D_ 60
#define N_ 1024
#define K_ 20
#define P1_ 8192      // B*N
#define P2_ 163840    // B*N*K

typedef __attribute__((ext_vector_type(8))) short bf16x8;
typedef __attribute__((ext_vector_type(4))) short bf16x4;
typedef __attribute__((ext_vector_type(4))) float f32x4;

__device__ inline float b2f(short s) { return __uint_as_float(((unsigned)(unsigned short)s) << 16); }
__device__ inline short f2b(float f) { __hip_bfloat16 h = __float2bfloat16(f); return *(short*)&h; }

// ---- workspace layout (bytes), all 256-aligned ----
#define OFF_IDX   0ull          // int[P2] = 655360
#define OFF_XX    655360ull     // float[P1] = 32768
#define OFF_STATS 688128ull     // sum[1792], ssq[1792], A[1792], B[1792] = 28672 (reserve 32768)
#define OFF_XT    720896ull     // bf16[P1][64] = 1048576
#define OFF_WB    1769472ull    // bf16 weights, 892928
#define OFF_XC    2662400ull    // bf16[P1][512] = 8388608
#define OFF_H5    11051008ull   // bf16[P1][256] = 4194304
#define OFF_H6    15245312ull   // bf16[P1][1024] = 16777216
#define OFF_BIGA  32022528ull   // bf16[P2][128] = 41943040  (feat, later h3)
#define OFF_H1    73965568ull   // bf16[P2][64] = 20971520
#define OFF_H2    94937088ull   // bf16[P2][64] = 20971520
#define OFF_H4    115908608ull  // bf16[P2][256] = 83886080
// end 199794688 (~190.5 MiB)

// weight sub-offsets (bf16 elements from wbase)
#define WO1 0
#define WO2 8192
#define WO3 12288
#define WO4 20480
#define WO5 53248
#define WO6 184320

// stats channel offsets per layer
#define SO1 0
#define SO2 64
#define SO3 128
#define SO4 256
#define SO5 512
#define SO6 768
#define NCH_TOT 1792

// ---------------- xx[bn] = sum_d x^2 ----------------
__global__ __launch_bounds__(256) void k_xx(const float* __restrict__ x,
                                            float* __restrict__ xx) {
  int bn = blockIdx.x * 256 + threadIdx.x;
  int b = bn >> 10, n = bn & 1023;
  const float* xb = x + (size_t)b * D_ * N_ + n;
  float s = 0.f;
  for (int d = 0; d < D_; ++d) { float v = xb[(size_t)d * N_]; s += v * v; }
  xx[bn] = s;
}

// ---------------- kNN: one block per (b,n) ----------------
__global__ __launch_bounds__(256) void k_knn(const float* __restrict__ x,
                                             const float* __restrict__ xx,
                                             int* __restrict__ idxb) {
  __shared__ float xn[D_];
  __shared__ float pd[N_];
  __shared__ float wv[4];
  __shared__ int   wi[4];
  int bn = blockIdx.x;
  int b = bn >> 10, n = bn & 1023;
  int tid = threadIdx.x;
  const float* xb = x + (size_t)b * D_ * N_;
  if (tid < D_) xn[tid] = xb[(size_t)tid * N_ + n];
  __syncthreads();
  float xnsq = xx[bn];
  int bbase = bn & ~1023;
  for (int i = 0; i < 4; ++i) {
    int m = tid + i * 256;
    float dot = 0.f;
    for (int d = 0; d < D_; ++d) dot += xn[d] * xb[(size_t)d * N_ + m];
    pd[m] = 2.f * dot - xnsq - xx[bbase + m];
  }
  __syncthreads();
  for (int kk = 0; kk < K_; ++kk) {
    float bv = -INFINITY; int bi = N_;
    for (int i = 0; i < 4; ++i) {
      int m = tid + i * 256;
      float v = pd[m];
      if (v > bv || (v == bv && m < bi)) { bv = v; bi = m; }
    }
    #pragma unroll
    for (int off = 32; off >= 1; off >>= 1) {
      float ov = __shfl_xor(bv, off);
      int   oi = __shfl_xor(bi, off);
      if (ov > bv || (ov == bv && oi < bi)) { bv = ov; bi = oi; }
    }
    if ((tid & 63) == 0) { wv[tid >> 6] = bv; wi[tid >> 6] = bi; }
    __syncthreads();
    if (tid == 0) {
      float fv = wv[0]; int fi = wi[0];
      for (int q = 1; q < 4; ++q)
        if (wv[q] > fv || (wv[q] == fv && wi[q] < fi)) { fv = wv[q]; fi = wi[q]; }
      idxb[(size_t)bn * K_ + kk] = fi;
      pd[fi] = -INFINITY;
    }
    __syncthreads();
  }
}

// ---------------- xt: [B][60][N] fp32 -> [P1][64] bf16 (pad 4 zeros) ----------------
__global__ __launch_bounds__(256) void k_xt(const float* __restrict__ x,
                                            short* __restrict__ xt) {
  int bn = blockIdx.x * 256 + threadIdx.x;
  int b = bn >> 10, n = bn & 1023;
  const float* xb = x + (size_t)b * D_ * N_ + n;
  short* row = xt + (size_t)bn * 64;
  for (int c = 0; c < 60; ++c) row[c] = f2b(xb[(size_t)c * N_]);
  row[60] = 0; row[61] = 0; row[62] = 0; row[63] = 0;
}

// ---------------- w1 pad: [64][120] fp32 -> [64][128] bf16 ----------------
__global__ __launch_bounds__(256) void k_w1pad(const float* __restrict__ w1,
                                               short* __restrict__ wb) {
  int t = blockIdx.x * 256 + threadIdx.x;  // 8192
  int o = t >> 7, c = t & 127;
  float v = 0.f;
  if (c < 60) v = w1[o * 120 + c];
  else if (c >= 64 && c < 124) v = w1[o * 120 + 60 + (c - 64)];
  wb[t] = f2b(v);
}

// ---------------- convert w2..w6 fp32 -> bf16 ----------------
__global__ __launch_bounds__(256) void k_wcvt(const float* __restrict__ w2,
                                              const float* __restrict__ w3,
                                              const float* __restrict__ w4,
                                              const float* __restrict__ w5,
                                              const float* __restrict__ w6,
                                              short* __restrict__ wbase) {
  int t = blockIdx.x * 256 + threadIdx.x;  // 438272 total
  if (t < 4096) wbase[WO2 + t] = f2b(w2[t]);
  else if (t < 12288) wbase[WO3 + (t - 4096)] = f2b(w3[t - 4096]);
  else if (t < 45056) wbase[WO4 + (t - 12288)] = f2b(w4[t - 12288]);
  else if (t < 176128) wbase[WO5 + (t - 45056)] = f2b(w5[t - 45056]);
  else if (t < 438272) wbase[WO6 + (t - 176128)] = f2b(w6[t - 176128]);
}

// ---------------- graph feature: [P2][128] bf16 ----------------
__global__ __launch_bounds__(256) void k_feat(const short* __restrict__ xt,
                                              const int* __restrict__ idxb,
                                              short* __restrict__ feat) {
  int t = blockIdx.x * 256 + threadIdx.x;
  int p = t >> 4, chunk = t & 15;
  int bn = p / K_;
  int nbr = (bn & ~1023) + idxb[p];
  bf16x8 o;
  if (chunk < 8) {
    bf16x8 c8 = *(const bf16x8*)(xt + (size_t)bn * 64 + chunk * 8);
    bf16x8 n8 = *(const bf16x8*)(xt + (size_t)nbr * 64 + chunk * 8);
    #pragma unroll
    for (int r = 0; r < 8; ++r) o[r] = f2b(b2f(n8[r]) - b2f(c8[r]));
  } else {
    o = *(const bf16x8*)(xt + (size_t)bn * 64 + (chunk - 8) * 8);
  }
  *(bf16x8*)(feat + (size_t)p * 128 + chunk * 8) = o;
}

// ---------------- MFMA GEMM: out[P][COUT] = in[P][K] . W[COUT][K]^T + bias ----------------
// block: 4 waves; wave: 64(co) x 32(p); block: 64(co) x 128(p); grid y over co/64
template <int K, int COUT>
__global__ __launch_bounds__(256) void k_gemm(const short* __restrict__ in,
                                              const short* __restrict__ wb,
                                              const float* __restrict__ bias,
                                              short* __restrict__ out, int P) {
  int tid = threadIdx.x;
  int wave = tid >> 6, lane = tid & 63;
  int ln = lane & 15, quad = lane >> 4;
  int p0 = blockIdx.x * 128 + wave * 32;
  int co0 = blockIdx.y * 64;
  f32x4 acc[4][2];
  #pragma unroll
  for (int m = 0; m < 4; ++m)
    #pragma unroll
    for (int t = 0; t < 2; ++t) acc[m][t] = (f32x4){0.f, 0.f, 0.f, 0.f};

  const short* wbase = wb + (size_t)(co0 + ln) * K + quad * 8;
  const short* ibase = in + (size_t)(p0 + ln) * K + quad * 8;
  for (int k0 = 0; k0 < K; k0 += 32) {
    bf16x8 a[4], bfr[2];
    #pragma unroll
    for (int m = 0; m < 4; ++m) a[m] = *(const bf16x8*)(wbase + (size_t)(m * 16) * K + k0);
    #pragma unroll
    for (int t = 0; t < 2; ++t) bfr[t] = *(const bf16x8*)(ibase + (size_t)(t * 16) * K + k0);
    #pragma unroll
    for (int m = 0; m < 4; ++m)
      #pragma unroll
      for (int t = 0; t < 2; ++t)
        acc[m][t] = __builtin_amdgcn_mfma_f32_16x16x32_bf16(a[m], bfr[t], acc[m][t], 0, 0, 0);
  }
  #pragma unroll
  for (int m = 0; m < 4; ++m) {
    f32x4 bs = *(const f32x4*)(bias + co0 + m * 16 + quad * 4);
    #pragma unroll
    for (int t = 0; t < 2; ++t) {
      int p = p0 + t * 16 + ln;
      bf16x4 o;
      #pragma unroll
      for (int r = 0; r < 4; ++r) o[r] = f2b(acc[m][t][r] + bs[r]);
      *(bf16x4*)(out + (size_t)p * COUT + co0 + m * 16 + quad * 4) = o;
    }
  }
}

// ---------------- column stats over [P][C] bf16 -> sum/ssq per channel ----------------
template <int C>
__global__ __launch_bounds__(256) void k_stats_pm(const short* __restrict__ h, long nchunks,
                                                  float* __restrict__ sum,
                                                  float* __restrict__ ssq) {
  constexpr int CH = C / 4;
  int tid = threadIdx.x;
  int c0 = (tid % CH) * 4;
  float s0 = 0, s1 = 0, s2 = 0, s3 = 0, q0 = 0, q1 = 0, q2 = 0, q3 = 0;
  long stride = (long)gridDim.x * 256;
  for (long i = (long)blockIdx.x * 256 + tid; i < nchunks; i += stride) {
    bf16x4 v = *(const bf16x4*)(h + i * 4);
    float f0 = b2f(v[0]), f1 = b2f(v[1]), f2 = b2f(v[2]), f3 = b2f(v[3]);
    s0 += f0; q0 += f0 * f0;
    s1 += f1; q1 += f1 * f1;
    s2 += f2; q2 += f2 * f2;
    s3 += f3; q3 += f3 * f3;
  }
  __shared__ float ls[2048];
  for (int j = tid; j < 2 * C; j += 256) ls[j] = 0.f;
  __syncthreads();
  atomicAdd(&ls[c0], s0); atomicAdd(&ls[c0 + 1], s1);
  atomicAdd(&ls[c0 + 2], s2); atomicAdd(&ls[c0 + 3], s3);
  atomicAdd(&ls[C + c0], q0); atomicAdd(&ls[C + c0 + 1], q1);
  atomicAdd(&ls[C + c0 + 2], q2); atomicAdd(&ls[C + c0 + 3], q3);
  __syncthreads();
  for (int j = tid; j < C; j += 256) {
    atomicAdd(&sum[j], ls[j]);
    atomicAdd(&ssq[j], ls[C + j]);
  }
}

// ---------------- A = g*rsqrt(var+eps), B = be - mean*A ----------------
__global__ __launch_bounds__(256) void k_bnab(const float* __restrict__ sum,
                                              const float* __restrict__ ssq,
                                              const float* __restrict__ g,
                                              const float* __restrict__ be,
                                              float* __restrict__ A,
                                              float* __restrict__ Bp, int C, float inv) {
  int c = blockIdx.x * 256 + threadIdx.x;
  if (c < C) {
    float m = sum[c] * inv;
    float v = ssq[c] * inv - m * m;
    float a = g[c] * rsqrtf(v + 1e-5f);
    A[c] = a; Bp[c] = be[c] - m * a;
  }
}

// ---------------- BN+lrelu (+writeback) + max over k -> xcat ----------------
template <int C, bool WB>
__global__ __launch_bounds__(256) void k_apply_max(short* __restrict__ h,
                                                   const float* __restrict__ A,
                                                   const float* __restrict__ Bp,
                                                   short* __restrict__ xcat, int xoff) {
  constexpr int CH = C / 4;
  int t = blockIdx.x * 256 + threadIdx.x;  // P1*CH total
  int bn = t / CH;
  int c0 = (t % CH) * 4;
  f32x4 a = *(const f32x4*)(A + c0);
  f32x4 b = *(const f32x4*)(Bp + c0);
  float m0 = -INFINITY, m1 = -INFINITY, m2 = -INFINITY, m3 = -INFINITY;
  size_t base = (size_t)bn * K_ * C + c0;
  for (int j = 0; j < K_; ++j) {
    short* ptr = h + base + (size_t)j * C;
    bf16x4 v = *(bf16x4*)ptr;
    float f0 = b2f(v[0]) * a[0] + b[0]; f0 = f0 >= 0.f ? f0 : 0.2f * f0;
    float f1 = b2f(v[1]) * a[1] + b[1]; f1 = f1 >= 0.f ? f1 : 0.2f * f1;
    float f2 = b2f(v[2]) * a[2] + b[2]; f2 = f2 >= 0.f ? f2 : 0.2f * f2;
    float f3 = b2f(v[3]) * a[3] + b[3]; f3 = f3 >= 0.f ? f3 : 0.2f * f3;
    m0 = fmaxf(m0, f0); m1 = fmaxf(m1, f1); m2 = fmaxf(m2, f2); m3 = fmaxf(m3, f3);
    if (WB) {
      bf16x4 w;
      w[0] = f2b(f0); w[1] = f2b(f1); w[2] = f2b(f2); w[3] = f2b(f3);
      *(bf16x4*)ptr = w;
    }
  }
  bf16x4 o;
  o[0] = f2b(m0); o[1] = f2b(m1); o[2] = f2b(m2); o[3] = f2b(m3);
  *(bf16x4*)(xcat + (size_t)bn * 512 + xoff + c0) = o;
}

// ---------------- BN+lrelu elementwise on bf16 [P][C] ----------------
template <int C>
__global__ __launch_bounds__(256) void k_apply_pm(short* __restrict__ h,
                                                  const float* __restrict__ A,
                                                  const float* __restrict__ Bp) {
  constexpr int CH = C / 4;
  int t = blockIdx.x * 256 + threadIdx.x;
  int c0 = (t % CH) * 4;
  f32x4 a = *(const f32x4*)(A + c0);
  f32x4 b = *(const f32x4*)(Bp + c0);
  bf16x4 v = *(bf16x4*)(h + (size_t)t * 4);
  bf16x4 w;
  #pragma unroll
  for (int r = 0; r < 4; ++r) {
    float f = b2f(v[r]) * a[r] + b[r];
    f = f >= 0.f ? f : 0.2f * f;
    w[r] = f2b(f);
  }
  *(bf16x4*)(h + (size_t)t * 4) = w;
}

// ---------------- final: BN+lrelu bf16 [P1][1024] -> fp32 out ----------------
__global__ __launch_bounds__(256) void k_apply_out(const short* __restrict__ h,
                                                   const float* __restrict__ A,
                                                   const float* __restrict__ Bp,
                                                   float* __restrict__ out) {
  int t = blockIdx.x * 256 + threadIdx.x;  // P1*256
  int c0 = (t & 255) * 4;
  f32x4 a = *(const f32x4*)(A + c0);
  f32x4 b = *(const f32x4*)(Bp + c0);
  bf16x4 v = *(const bf16x4*)(h + (size_t)t * 4);
  f32x4 o;
  #pragma unroll
  for (int r = 0; r < 4; ++r) {
    float f = b2f(v[r]) * a[r] + b[r];
    o[r] = f >= 0.f ? f : 0.2f * f;
  }
  *(f32x4*)(out + (size_t)t * 4) = o;
}

extern "C" void kernel_launch(void* const* d_in, const int* in_sizes, int n_in,
                              void* d_out, int out_size, void* d_ws, size_t ws_size,
                              hipStream_t stream) {
  const float* x   = (const float*)d_in[0];
  const float* w1  = (const float*)d_in[1];
  const float* b1  = (const float*)d_in[2];
  const float* g1  = (const float*)d_in[3];
  const float* be1 = (const float*)d_in[4];
  const float* w2  = (const float*)d_in[5];
  const float* b2  = (const float*)d_in[6];
  const float* g2  = (const float*)d_in[7];
  const float* be2 = (const float*)d_in[8];
  const float* w3  = (const float*)d_in[9];
  const float* b3  = (const float*)d_in[10];
  const float* g3  = (const float*)d_in[11];
  const float* be3 = (const float*)d_in[12];
  const float* w4  = (const float*)d_in[13];
  const float* b4  = (const float*)d_in[14];
  const float* g4  = (const float*)d_in[15];
  const float* be4 = (const float*)d_in[16];
  const float* w5  = (const float*)d_in[17];
  const float* b5  = (const float*)d_in[18];
  const float* g5  = (const float*)d_in[19];
  const float* be5 = (const float*)d_in[20];
  const float* w6  = (const float*)d_in[21];
  const float* b6  = (const float*)d_in[22];
  const float* g6  = (const float*)d_in[23];
  const float* be6 = (const float*)d_in[24];
  float* out = (float*)d_out;
  char* ws = (char*)d_ws;

  int*   idxb = (int*)(ws + OFF_IDX);
  float* xx   = (float*)(ws + OFF_XX);
  float* sum  = (float*)(ws + OFF_STATS);
  float* ssq  = sum + NCH_TOT;
  float* Aall = sum + 2 * NCH_TOT;
  float* Ball = sum + 3 * NCH_TOT;
  short* xt   = (short*)(ws + OFF_XT);
  short* wbb  = (short*)(ws + OFF_WB);
  short* xcat = (short*)(ws + OFF_XC);
  short* h5   = (short*)(ws + OFF_H5);
  short* h6   = (short*)(ws + OFF_H6);
  short* feat = (short*)(ws + OFF_BIGA);  // later reused as h3
  short* h1   = (short*)(ws + OFF_H1);
  short* h2   = (short*)(ws + OFF_H2);
  short* h3   = (short*)(ws + OFF_BIGA);
  short* h4   = (short*)(ws + OFF_H4);

  hipMemsetAsync(sum, 0, 2 * NCH_TOT * sizeof(float), stream);

  k_xx <<<P1_ / 256, 256, 0, stream>>>(x, xx);
  k_knn<<<P1_, 256, 0, stream>>>(x, xx, idxb);
  k_xt <<<P1_ / 256, 256, 0, stream>>>(x, xt);
  k_w1pad<<<32, 256, 0, stream>>>(w1, wbb + WO1);
  k_wcvt<<<1712, 256, 0, stream>>>(w2, w3, w4, w5, w6, wbb);
  k_feat<<<P2_ * 16 / 256, 256, 0, stream>>>(xt, idxb, feat);

  // layer 1: feat[P2][128] x w1[64][128] -> h1[P2][64]
  k_gemm<128, 64><<<dim3(P2_ / 128, 1), 256, 0, stream>>>(feat, wbb + WO1, b1, h1, P2_);
  k_stats_pm<64><<<384, 256, 0, stream>>>(h1, (long)P2_ * 16, sum + SO1, ssq + SO1);
  k_bnab<<<1, 256, 0, stream>>>(sum + SO1, ssq + SO1, g1, be1, Aall + SO1, Ball + SO1, 64, 1.f / P2_);
  k_apply_max<64, true><<<P1_ * 16 / 256, 256, 0, stream>>>(h1, Aall + SO1, Ball + SO1, xcat, 0);

  // layer 2: h1[P2][64] x w2[64][64] -> h2[P2][64]
  k_gemm<64, 64><<<dim3(P2_ / 128, 1), 256, 0, stream>>>(h1, wbb + WO2, b2, h2, P2_);
  k_stats_pm<64><<<384, 256, 0, stream>>>(h2, (long)P2_ * 16, sum + SO2, ssq + SO2);
  k_bnab<<<1, 256, 0, stream>>>(sum + SO2, ssq + SO2, g2, be2, Aall + SO2, Ball + SO2, 64, 1.f / P2_);
  k_apply_max<64, true><<<P1_ * 16 / 256, 256, 0, stream>>>(h2, Aall + SO2, Ball + SO2, xcat, 64);

  // layer 3: h2[P2][64] x w3[128][64] -> h3[P2][128]
  k_gemm<64, 128><<<dim3(P2_ / 128, 2), 256, 0, stream>>>(h2, wbb + WO3, b3, h3, P2_);
  k_stats_pm<128><<<384, 256, 0, stream>>>(h3, (long)P2_ * 32, sum + SO3, ssq + SO3);
  k_bnab<<<1, 256, 0, stream>>>(sum + SO3, ssq + SO3, g3, be3, Aall + SO3, Ball + SO3, 128, 1.f / P2_);
  k_apply_max<128, true><<<P1_ * 32 / 256, 256, 0, stream>>>(h3, Aall + SO3, Ball + SO3, xcat, 128);

  // layer 4: h3[P2][128] x w4[256][128] -> h4[P2][256]
  k_gemm<128, 256><<<dim3(P2_ / 128, 4), 256, 0, stream>>>(h3, wbb + WO4, b4, h4, P2_);
  k_stats_pm<256><<<384, 256, 0, stream>>>(h4, (long)P2_ * 64, sum + SO4, ssq + SO4);
  k_bnab<<<1, 256, 0, stream>>>(sum + SO4, ssq + SO4, g4, be4, Aall + SO4, Ball + SO4, 256, 1.f / P2_);
  k_apply_max<256, false><<<P1_ * 64 / 256, 256, 0, stream>>>(h4, Aall + SO4, Ball + SO4, xcat, 256);

  // layer 5: xcat[P1][512] x w5[256][512] -> h5[P1][256]
  k_gemm<512, 256><<<dim3(P1_ / 128, 4), 256, 0, stream>>>(xcat, wbb + WO5, b5, h5, P1_);
  k_stats_pm<256><<<384, 256, 0, stream>>>(h5, (long)P1_ * 64, sum + SO5, ssq + SO5);
  k_bnab<<<1, 256, 0, stream>>>(sum + SO5, ssq + SO5, g5, be5, Aall + SO5, Ball + SO5, 256, 1.f / P1_);
  k_apply_pm<256><<<P1_ * 64 / 256, 256, 0, stream>>>(h5, Aall + SO5, Ball + SO5);

  // layer 6: h5[P1][256] x w6[1024][256] -> h6[P1][1024]
  k_gemm<256, 1024><<<dim3(P1_ / 128, 16), 256, 0, stream>>>(h5, wbb + WO6, b6, h6, P1_);
  k_stats_pm<1024><<<384, 256, 0, stream>>>(h6, (long)P1_ * 256, sum + SO6, ssq + SO6);
  k_bnab<<<4, 256, 0, stream>>>(sum + SO6, ssq + SO6, g6, be6, Aall + SO6, Ball + SO6, 1024, 1.f / P1_);
  k_apply_out<<<P1_ * 256 / 256, 256, 0, stream>>>(h6, Aall + SO6, Ball + SO6, out);

  (void)in_sizes; (void)n_in; (void)out_size; (void)ws_size;
}

// Round 3
// 703.036 us; speedup vs baseline: 3.5279x; 1.1658x over previous
//
#include <hip/hip_runtime.h>
#include <hip/hip_bf16.h>
#include <math.h>

#define B_ 8
#define D_ 60
#define N_ 1024
#define K_ 20
#define P1_ 8192      // B*N
#define P2_ 163840    // B*N*K

typedef __attribute__((ext_vector_type(8))) short bf16x8;
typedef __attribute__((ext_vector_type(4))) short bf16x4;
typedef __attribute__((ext_vector_type(4))) float f32x4;

__device__ inline float b2f(short s) { return __uint_as_float(((unsigned)(unsigned short)s) << 16); }
__device__ inline short f2b(float f) { __hip_bfloat16 h = __float2bfloat16(f); return *(short*)&h; }

// ---- workspace layout (bytes), all 256-aligned ----
#define OFF_IDX   0ull          // int[P2] = 655360
#define OFF_XX    655360ull     // float[P1] = 32768
#define OFF_STATS 688128ull     // sum[1792], ssq[1792], A[1792], B[1792] = 28672 (reserve 32768)
#define OFF_XT    720896ull     // bf16[P1][64] = 1048576
#define OFF_WB    1769472ull    // bf16 weights, 892928
#define OFF_XC    2662400ull    // bf16[P1][512] = 8388608
#define OFF_H5    11051008ull   // bf16[P1][256] = 4194304
#define OFF_H6    15245312ull   // bf16[P1][1024] = 16777216
#define OFF_BIGA  32022528ull   // bf16[P2][128] = 41943040  (feat, later h3)
#define OFF_H1    73965568ull   // bf16[P2][64] = 20971520
#define OFF_H2    94937088ull   // bf16[P2][64] = 20971520
#define OFF_H4    115908608ull  // bf16[P2][256] = 83886080
// end 199794688 (~190.5 MiB)

// weight sub-offsets (bf16 elements from wbase)
#define WO1 0
#define WO2 8192
#define WO3 12288
#define WO4 20480
#define WO5 53248
#define WO6 184320

// stats channel offsets per layer
#define SO1 0
#define SO2 64
#define SO3 128
#define SO4 256
#define SO5 512
#define SO6 768
#define NCH_TOT 1792

// ---------------- xx[bn] = sum_d x^2 ----------------
__global__ __launch_bounds__(256) void k_xx(const float* __restrict__ x,
                                            float* __restrict__ xx) {
  int bn = blockIdx.x * 256 + threadIdx.x;
  int b = bn >> 10, n = bn & 1023;
  const float* xb = x + (size_t)b * D_ * N_ + n;
  float s = 0.f;
  for (int d = 0; d < D_; ++d) { float v = xb[(size_t)d * N_]; s += v * v; }
  xx[bn] = s;
}

// ---------------- kNN: one WAVE per point, no barriers in selection ----------------
__global__ __launch_bounds__(256) void k_knn2(const float* __restrict__ x,
                                              const float* __restrict__ xx,
                                              int* __restrict__ idxb) {
  __shared__ float xns[4][64];
  int tid = threadIdx.x;
  int wave = tid >> 6, lane = tid & 63;
  int bn = blockIdx.x * 4 + wave;
  int b = bn >> 10, n = bn & 1023;
  const float* xb = x + (size_t)b * D_ * N_;
  if (lane < D_) xns[wave][lane] = xb[(size_t)lane * N_ + n];
  __syncthreads();
  float xnsq = xx[bn];
  int mbase = lane * 16;
  const float* xxb = xx + (bn & ~1023);

  float dot[16];
  #pragma unroll
  for (int j = 0; j < 16; ++j) dot[j] = 0.f;
  for (int d = 0; d < D_; ++d) {
    float xnd = xns[wave][d];
    const float* row = xb + (size_t)d * N_ + mbase;
    f32x4 r0 = *(const f32x4*)(row);
    f32x4 r1 = *(const f32x4*)(row + 4);
    f32x4 r2 = *(const f32x4*)(row + 8);
    f32x4 r3 = *(const f32x4*)(row + 12);
    #pragma unroll
    for (int r = 0; r < 4; ++r) {
      dot[r]      = fmaf(xnd, r0[r], dot[r]);
      dot[4 + r]  = fmaf(xnd, r1[r], dot[4 + r]);
      dot[8 + r]  = fmaf(xnd, r2[r], dot[8 + r]);
      dot[12 + r] = fmaf(xnd, r3[r], dot[12 + r]);
    }
  }
  float v[16];
  #pragma unroll
  for (int j = 0; j < 16; ++j)
    v[j] = 2.f * dot[j] - xnsq - xxb[mbase + j];

  int* outp = idxb + (size_t)bn * K_;
  for (int kk = 0; kk < K_; ++kk) {
    float bv = v[0]; int bj = 0;
    #pragma unroll
    for (int j = 1; j < 16; ++j)
      if (v[j] > bv) { bv = v[j]; bj = j; }   // ascending scan: lowest j wins ties
    int bi = mbase + bj;
    #pragma unroll
    for (int off = 1; off < 64; off <<= 1) {
      float ov = __shfl_xor(bv, off);
      int   oi = __shfl_xor(bi, off);
      if (ov > bv || (ov == bv && oi < bi)) { bv = ov; bi = oi; }
    }
    if (lane == 0) outp[kk] = bi;
    #pragma unroll
    for (int j = 0; j < 16; ++j)
      if (bi == mbase + j) v[j] = -INFINITY;
  }
}

// ---------------- xt: [B][60][N] fp32 -> [P1][64] bf16 (pad 4 zeros) ----------------
__global__ __launch_bounds__(256) void k_xt(const float* __restrict__ x,
                                            short* __restrict__ xt) {
  int bn = blockIdx.x * 256 + threadIdx.x;
  int b = bn >> 10, n = bn & 1023;
  const float* xb = x + (size_t)b * D_ * N_ + n;
  short* row = xt + (size_t)bn * 64;
  for (int c = 0; c < 60; ++c) row[c] = f2b(xb[(size_t)c * N_]);
  row[60] = 0; row[61] = 0; row[62] = 0; row[63] = 0;
}

// ---------------- w1 pad: [64][120] fp32 -> [64][128] bf16 ----------------
__global__ __launch_bounds__(256) void k_w1pad(const float* __restrict__ w1,
                                               short* __restrict__ wb) {
  int t = blockIdx.x * 256 + threadIdx.x;  // 8192
  int o = t >> 7, c = t & 127;
  float v = 0.f;
  if (c < 60) v = w1[o * 120 + c];
  else if (c >= 64 && c < 124) v = w1[o * 120 + 60 + (c - 64)];
  wb[t] = f2b(v);
}

// ---------------- convert w2..w6 fp32 -> bf16 ----------------
__global__ __launch_bounds__(256) void k_wcvt(const float* __restrict__ w2,
                                              const float* __restrict__ w3,
                                              const float* __restrict__ w4,
                                              const float* __restrict__ w5,
                                              const float* __restrict__ w6,
                                              short* __restrict__ wbase) {
  int t = blockIdx.x * 256 + threadIdx.x;  // 438272 total
  if (t < 4096) wbase[WO2 + t] = f2b(w2[t]);
  else if (t < 12288) wbase[WO3 + (t - 4096)] = f2b(w3[t - 4096]);
  else if (t < 45056) wbase[WO4 + (t - 12288)] = f2b(w4[t - 12288]);
  else if (t < 176128) wbase[WO5 + (t - 45056)] = f2b(w5[t - 45056]);
  else if (t < 438272) wbase[WO6 + (t - 176128)] = f2b(w6[t - 176128]);
}

// ---------------- graph feature: [P2][128] bf16 ----------------
__global__ __launch_bounds__(256) void k_feat(const short* __restrict__ xt,
                                              const int* __restrict__ idxb,
                                              short* __restrict__ feat) {
  int t = blockIdx.x * 256 + threadIdx.x;
  int p = t >> 4, chunk = t & 15;
  int bn = p / K_;
  int nbr = (bn & ~1023) + idxb[p];
  bf16x8 o;
  if (chunk < 8) {
    bf16x8 c8 = *(const bf16x8*)(xt + (size_t)bn * 64 + chunk * 8);
    bf16x8 n8 = *(const bf16x8*)(xt + (size_t)nbr * 64 + chunk * 8);
    #pragma unroll
    for (int r = 0; r < 8; ++r) o[r] = f2b(b2f(n8[r]) - b2f(c8[r]));
  } else {
    o = *(const bf16x8*)(xt + (size_t)bn * 64 + (chunk - 8) * 8);
  }
  *(bf16x8*)(feat + (size_t)p * 128 + chunk * 8) = o;
}

// ---------------- MFMA GEMM: out[P][COUT] = in[P][K] . W[COUT][K]^T + bias ----------------
template <int K, int COUT>
__global__ __launch_bounds__(256) void k_gemm(const short* __restrict__ in,
                                              const short* __restrict__ wb,
                                              const float* __restrict__ bias,
                                              short* __restrict__ out, int P) {
  int tid = threadIdx.x;
  int wave = tid >> 6, lane = tid & 63;
  int ln = lane & 15, quad = lane >> 4;
  int p0 = blockIdx.x * 128 + wave * 32;
  int co0 = blockIdx.y * 64;
  f32x4 acc[4][2];
  #pragma unroll
  for (int m = 0; m < 4; ++m)
    #pragma unroll
    for (int t = 0; t < 2; ++t) acc[m][t] = (f32x4){0.f, 0.f, 0.f, 0.f};

  const short* wbase = wb + (size_t)(co0 + ln) * K + quad * 8;
  const short* ibase = in + (size_t)(p0 + ln) * K + quad * 8;
  for (int k0 = 0; k0 < K; k0 += 32) {
    bf16x8 a[4], bfr[2];
    #pragma unroll
    for (int m = 0; m < 4; ++m) a[m] = *(const bf16x8*)(wbase + (size_t)(m * 16) * K + k0);
    #pragma unroll
    for (int t = 0; t < 2; ++t) bfr[t] = *(const bf16x8*)(ibase + (size_t)(t * 16) * K + k0);
    #pragma unroll
    for (int m = 0; m < 4; ++m)
      #pragma unroll
      for (int t = 0; t < 2; ++t)
        acc[m][t] = __builtin_amdgcn_mfma_f32_16x16x32_bf16(a[m], bfr[t], acc[m][t], 0, 0, 0);
  }
  #pragma unroll
  for (int m = 0; m < 4; ++m) {
    f32x4 bs = *(const f32x4*)(bias + co0 + m * 16 + quad * 4);
    #pragma unroll
    for (int t = 0; t < 2; ++t) {
      int p = p0 + t * 16 + ln;
      bf16x4 o;
      #pragma unroll
      for (int r = 0; r < 4; ++r) o[r] = f2b(acc[m][t][r] + bs[r]);
      *(bf16x4*)(out + (size_t)p * COUT + co0 + m * 16 + quad * 4) = o;
    }
  }
}

// ---------------- column stats over [P][C] bf16 -> sum/ssq per channel ----------------
template <int C>
__global__ __launch_bounds__(256) void k_stats_pm(const short* __restrict__ h, long nchunks,
                                                  float* __restrict__ sum,
                                                  float* __restrict__ ssq) {
  constexpr int CH = C / 4;
  int tid = threadIdx.x;
  int c0 = (tid % CH) * 4;
  float s0 = 0, s1 = 0, s2 = 0, s3 = 0, q0 = 0, q1 = 0, q2 = 0, q3 = 0;
  long stride = (long)gridDim.x * 256;
  for (long i = (long)blockIdx.x * 256 + tid; i < nchunks; i += stride) {
    bf16x4 v = *(const bf16x4*)(h + i * 4);
    float f0 = b2f(v[0]), f1 = b2f(v[1]), f2 = b2f(v[2]), f3 = b2f(v[3]);
    s0 += f0; q0 += f0 * f0;
    s1 += f1; q1 += f1 * f1;
    s2 += f2; q2 += f2 * f2;
    s3 += f3; q3 += f3 * f3;
  }
  __shared__ float ls[2048];
  for (int j = tid; j < 2 * C; j += 256) ls[j] = 0.f;
  __syncthreads();
  atomicAdd(&ls[c0], s0); atomicAdd(&ls[c0 + 1], s1);
  atomicAdd(&ls[c0 + 2], s2); atomicAdd(&ls[c0 + 3], s3);
  atomicAdd(&ls[C + c0], q0); atomicAdd(&ls[C + c0 + 1], q1);
  atomicAdd(&ls[C + c0 + 2], q2); atomicAdd(&ls[C + c0 + 3], q3);
  __syncthreads();
  for (int j = tid; j < C; j += 256) {
    atomicAdd(&sum[j], ls[j]);
    atomicAdd(&ssq[j], ls[C + j]);
  }
}

// ---------------- A = g*rsqrt(var+eps), B = be - mean*A ----------------
__global__ __launch_bounds__(256) void k_bnab(const float* __restrict__ sum,
                                              const float* __restrict__ ssq,
                                              const float* __restrict__ g,
                                              const float* __restrict__ be,
                                              float* __restrict__ A,
                                              float* __restrict__ Bp, int C, float inv) {
  int c = blockIdx.x * 256 + threadIdx.x;
  if (c < C) {
    float m = sum[c] * inv;
    float v = ssq[c] * inv - m * m;
    float a = g[c] * rsqrtf(v + 1e-5f);
    A[c] = a; Bp[c] = be[c] - m * a;
  }
}

// ---------------- BN+lrelu (+writeback) + max over k -> xcat ----------------
template <int C, bool WB>
__global__ __launch_bounds__(256) void k_apply_max(short* __restrict__ h,
                                                   const float* __restrict__ A,
                                                   const float* __restrict__ Bp,
                                                   short* __restrict__ xcat, int xoff) {
  constexpr int CH = C / 4;
  int t = blockIdx.x * 256 + threadIdx.x;  // P1*CH total
  int bn = t / CH;
  int c0 = (t % CH) * 4;
  f32x4 a = *(const f32x4*)(A + c0);
  f32x4 b = *(const f32x4*)(Bp + c0);
  float m0 = -INFINITY, m1 = -INFINITY, m2 = -INFINITY, m3 = -INFINITY;
  size_t base = (size_t)bn * K_ * C + c0;
  for (int j = 0; j < K_; ++j) {
    short* ptr = h + base + (size_t)j * C;
    bf16x4 v = *(bf16x4*)ptr;
    float f0 = b2f(v[0]) * a[0] + b[0]; f0 = f0 >= 0.f ? f0 : 0.2f * f0;
    float f1 = b2f(v[1]) * a[1] + b[1]; f1 = f1 >= 0.f ? f1 : 0.2f * f1;
    float f2 = b2f(v[2]) * a[2] + b[2]; f2 = f2 >= 0.f ? f2 : 0.2f * f2;
    float f3 = b2f(v[3]) * a[3] + b[3]; f3 = f3 >= 0.f ? f3 : 0.2f * f3;
    m0 = fmaxf(m0, f0); m1 = fmaxf(m1, f1); m2 = fmaxf(m2, f2); m3 = fmaxf(m3, f3);
    if (WB) {
      bf16x4 w;
      w[0] = f2b(f0); w[1] = f2b(f1); w[2] = f2b(f2); w[3] = f2b(f3);
      *(bf16x4*)ptr = w;
    }
  }
  bf16x4 o;
  o[0] = f2b(m0); o[1] = f2b(m1); o[2] = f2b(m2); o[3] = f2b(m3);
  *(bf16x4*)(xcat + (size_t)bn * 512 + xoff + c0) = o;
}

// ---------------- BN+lrelu elementwise on bf16 [P][C] ----------------
template <int C>
__global__ __launch_bounds__(256) void k_apply_pm(short* __restrict__ h,
                                                  const float* __restrict__ A,
                                                  const float* __restrict__ Bp) {
  constexpr int CH = C / 4;
  int t = blockIdx.x * 256 + threadIdx.x;
  int c0 = (t % CH) * 4;
  f32x4 a = *(const f32x4*)(A + c0);
  f32x4 b = *(const f32x4*)(Bp + c0);
  bf16x4 v = *(bf16x4*)(h + (size_t)t * 4);
  bf16x4 w;
  #pragma unroll
  for (int r = 0; r < 4; ++r) {
    float f = b2f(v[r]) * a[r] + b[r];
    f = f >= 0.f ? f : 0.2f * f;
    w[r] = f2b(f);
  }
  *(bf16x4*)(h + (size_t)t * 4) = w;
}

// ---------------- final: BN+lrelu bf16 [P1][1024] -> fp32 out ----------------
__global__ __launch_bounds__(256) void k_apply_out(const short* __restrict__ h,
                                                   const float* __restrict__ A,
                                                   const float* __restrict__ Bp,
                                                   float* __restrict__ out) {
  int t = blockIdx.x * 256 + threadIdx.x;  // P1*256
  int c0 = (t & 255) * 4;
  f32x4 a = *(const f32x4*)(A + c0);
  f32x4 b = *(const f32x4*)(Bp + c0);
  bf16x4 v = *(const bf16x4*)(h + (size_t)t * 4);
  f32x4 o;
  #pragma unroll
  for (int r = 0; r < 4; ++r) {
    float f = b2f(v[r]) * a[r] + b[r];
    o[r] = f >= 0.f ? f : 0.2f * f;
  }
  *(f32x4*)(out + (size_t)t * 4) = o;
}

extern "C" void kernel_launch(void* const* d_in, const int* in_sizes, int n_in,
                              void* d_out, int out_size, void* d_ws, size_t ws_size,
                              hipStream_t stream) {
  const float* x   = (const float*)d_in[0];
  const float* w1  = (const float*)d_in[1];
  const float* b1  = (const float*)d_in[2];
  const float* g1  = (const float*)d_in[3];
  const float* be1 = (const float*)d_in[4];
  const float* w2  = (const float*)d_in[5];
  const float* b2  = (const float*)d_in[6];
  const float* g2  = (const float*)d_in[7];
  const float* be2 = (const float*)d_in[8];
  const float* w3  = (const float*)d_in[9];
  const float* b3  = (const float*)d_in[10];
  const float* g3  = (const float*)d_in[11];
  const float* be3 = (const float*)d_in[12];
  const float* w4  = (const float*)d_in[13];
  const float* b4  = (const float*)d_in[14];
  const float* g4  = (const float*)d_in[15];
  const float* be4 = (const float*)d_in[16];
  const float* w5  = (const float*)d_in[17];
  const float* b5  = (const float*)d_in[18];
  const float* g5  = (const float*)d_in[19];
  const float* be5 = (const float*)d_in[20];
  const float* w6  = (const float*)d_in[21];
  const float* b6  = (const float*)d_in[22];
  const float* g6  = (const float*)d_in[23];
  const float* be6 = (const float*)d_in[24];
  float* out = (float*)d_out;
  char* ws = (char*)d_ws;

  int*   idxb = (int*)(ws + OFF_IDX);
  float* xx   = (float*)(ws + OFF_XX);
  float* sum  = (float*)(ws + OFF_STATS);
  float* ssq  = sum + NCH_TOT;
  float* Aall = sum + 2 * NCH_TOT;
  float* Ball = sum + 3 * NCH_TOT;
  short* xt   = (short*)(ws + OFF_XT);
  short* wbb  = (short*)(ws + OFF_WB);
  short* xcat = (short*)(ws + OFF_XC);
  short* h5   = (short*)(ws + OFF_H5);
  short* h6   = (short*)(ws + OFF_H6);
  short* feat = (short*)(ws + OFF_BIGA);  // later reused as h3
  short* h1   = (short*)(ws + OFF_H1);
  short* h2   = (short*)(ws + OFF_H2);
  short* h3   = (short*)(ws + OFF_BIGA);
  short* h4   = (short*)(ws + OFF_H4);

  hipMemsetAsync(sum, 0, 2 * NCH_TOT * sizeof(float), stream);

  k_xx <<<P1_ / 256, 256, 0, stream>>>(x, xx);
  k_knn2<<<P1_ / 4, 256, 0, stream>>>(x, xx, idxb);
  k_xt <<<P1_ / 256, 256, 0, stream>>>(x, xt);
  k_w1pad<<<32, 256, 0, stream>>>(w1, wbb + WO1);
  k_wcvt<<<1712, 256, 0, stream>>>(w2, w3, w4, w5, w6, wbb);
  k_feat<<<P2_ * 16 / 256, 256, 0, stream>>>(xt, idxb, feat);

  // layer 1: feat[P2][128] x w1[64][128] -> h1[P2][64]
  k_gemm<128, 64><<<dim3(P2_ / 128, 1), 256, 0, stream>>>(feat, wbb + WO1, b1, h1, P2_);
  k_stats_pm<64><<<768, 256, 0, stream>>>(h1, (long)P2_ * 16, sum + SO1, ssq + SO1);
  k_bnab<<<1, 256, 0, stream>>>(sum + SO1, ssq + SO1, g1, be1, Aall + SO1, Ball + SO1, 64, 1.f / P2_);
  k_apply_max<64, true><<<P1_ * 16 / 256, 256, 0, stream>>>(h1, Aall + SO1, Ball + SO1, xcat, 0);

  // layer 2: h1[P2][64] x w2[64][64] -> h2[P2][64]
  k_gemm<64, 64><<<dim3(P2_ / 128, 1), 256, 0, stream>>>(h1, wbb + WO2, b2, h2, P2_);
  k_stats_pm<64><<<768, 256, 0, stream>>>(h2, (long)P2_ * 16, sum + SO2, ssq + SO2);
  k_bnab<<<1, 256, 0, stream>>>(sum + SO2, ssq + SO2, g2, be2, Aall + SO2, Ball + SO2, 64, 1.f / P2_);
  k_apply_max<64, true><<<P1_ * 16 / 256, 256, 0, stream>>>(h2, Aall + SO2, Ball + SO2, xcat, 64);

  // layer 3: h2[P2][64] x w3[128][64] -> h3[P2][128]
  k_gemm<64, 128><<<dim3(P2_ / 128, 2), 256, 0, stream>>>(h2, wbb + WO3, b3, h3, P2_);
  k_stats_pm<128><<<768, 256, 0, stream>>>(h3, (long)P2_ * 32, sum + SO3, ssq + SO3);
  k_bnab<<<1, 256, 0, stream>>>(sum + SO3, ssq + SO3, g3, be3, Aall + SO3, Ball + SO3, 128, 1.f / P2_);
  k_apply_max<128, true><<<P1_ * 32 / 256, 256, 0, stream>>>(h3, Aall + SO3, Ball + SO3, xcat, 128);

  // layer 4: h3[P2][128] x w4[256][128] -> h4[P2][256]
  k_gemm<128, 256><<<dim3(P2_ / 128, 4), 256, 0, stream>>>(h3, wbb + WO4, b4, h4, P2_);
  k_stats_pm<256><<<768, 256, 0, stream>>>(h4, (long)P2_ * 64, sum + SO4, ssq + SO4);
  k_bnab<<<1, 256, 0, stream>>>(sum + SO4, ssq + SO4, g4, be4, Aall + SO4, Ball + SO4, 256, 1.f / P2_);
  k_apply_max<256, false><<<P1_ * 64 / 256, 256, 0, stream>>>(h4, Aall + SO4, Ball + SO4, xcat, 256);

  // layer 5: xcat[P1][512] x w5[256][512] -> h5[P1][256]
  k_gemm<512, 256><<<dim3(P1_ / 128, 4), 256, 0, stream>>>(xcat, wbb + WO5, b5, h5, P1_);
  k_stats_pm<256><<<768, 256, 0, stream>>>(h5, (long)P1_ * 64, sum + SO5, ssq + SO5);
  k_bnab<<<1, 256, 0, stream>>>(sum + SO5, ssq + SO5, g5, be5, Aall + SO5, Ball + SO5, 256, 1.f / P1_);
  k_apply_pm<256><<<P1_ * 64 / 256, 256, 0, stream>>>(h5, Aall + SO5, Ball + SO5);

  // layer 6: h5[P1][256] x w6[1024][256] -> h6[P1][1024]
  k_gemm<256, 1024><<<dim3(P1_ / 128, 16), 256, 0, stream>>>(h5, wbb + WO6, b6, h6, P1_);
  k_stats_pm<1024><<<768, 256, 0, stream>>>(h6, (long)P1_ * 256, sum + SO6, ssq + SO6);
  k_bnab<<<4, 256, 0, stream>>>(sum + SO6, ssq + SO6, g6, be6, Aall + SO6, Ball + SO6, 1024, 1.f / P1_);
  k_apply_out<<<P1_ * 256 / 256, 256, 0, stream>>>(h6, Aall + SO6, Ball + SO6, out);

  (void)in_sizes; (void)n_in; (void)out_size; (void)ws_size;
}

// Round 4
// 607.462 us; speedup vs baseline: 4.0830x; 1.1573x over previous
//
#include <hip/hip_runtime.h>
#include <hip/hip_bf16.h>
#include <math.h>

#define B_ 8
#define D_ 60
#define N_ 1024
#define K_ 20
#define P1_ 8192      // B*N
#define P2_ 163840    // B*N*K

typedef __attribute__((ext_vector_type(8))) short bf16x8;
typedef __attribute__((ext_vector_type(4))) short bf16x4;
typedef __attribute__((ext_vector_type(4))) float f32x4;

__device__ inline float b2f(short s) { return __uint_as_float(((unsigned)(unsigned short)s) << 16); }
__device__ inline short f2b(float f) { __hip_bfloat16 h = __float2bfloat16(f); return *(short*)&h; }

// ---- workspace layout (bytes), all 256-aligned ----
#define OFF_IDX   0ull          // int[P2] = 655360
#define OFF_XX    655360ull     // float[P1] = 32768
#define OFF_STATS 688128ull     // sum[1792], ssq[1792], A[1792], B[1792]
#define OFF_XT    720896ull     // bf16[P1][64] = 1048576
#define OFF_WB    1769472ull    // bf16 weights
#define OFF_XC    2662400ull    // bf16[P1][512] = 8388608
#define OFF_H5    11051008ull   // bf16[P1][256] = 4194304
#define OFF_H6    15245312ull   // bf16[P1][1024] = 16777216
#define OFF_BIGA  32022528ull   // bf16[P2][128] = 41943040  (feat, later h3)
#define OFF_H1    73965568ull   // bf16[P2][64] = 20971520
#define OFF_H2    94937088ull   // bf16[P2][64] = 20971520
#define OFF_H4    115908608ull  // bf16[P2][256] = 83886080 ; pd (33.5MB) aliases here (consumed before h4 written)
// end 199794688 (~190.5 MiB)

#define WO1 0
#define WO2 8192
#define WO3 12288
#define WO4 20480
#define WO5 53248
#define WO6 184320

#define SO1 0
#define SO2 64
#define SO3 128
#define SO4 256
#define SO5 512
#define SO6 768
#define NCH_TOT 1792

// ---------------- xx[bn] = sum_d x^2 ----------------
__global__ __launch_bounds__(256) void k_xx(const float* __restrict__ x,
                                            float* __restrict__ xx) {
  int bn = blockIdx.x * 256 + threadIdx.x;
  int b = bn >> 10, n = bn & 1023;
  const float* xb = x + (size_t)b * D_ * N_ + n;
  float s = 0.f;
  for (int d = 0; d < D_; ++d) { float v = xb[(size_t)d * N_]; s += v * v; }
  xx[bn] = s;
}

// ---------------- pd[b][n][m] = 2*dot - xx_n - xx_m ; tiled fp32 ----------------
// grid: (m-tiles=8, n-tiles=16, b=8); block 256; tile 64n x 128m; LDS 45KB
__global__ __launch_bounds__(256) void k_pd(const float* __restrict__ x,
                                            const float* __restrict__ xx,
                                            float* __restrict__ pd) {
  __shared__ float lnn[D_][64];
  __shared__ float lmm[D_][128];
  int tid = threadIdx.x;
  int m0 = blockIdx.x * 128, n0 = blockIdx.y * 64, b = blockIdx.z;
  const float* xb = x + (size_t)b * D_ * N_;
  #pragma unroll
  for (int i = 0; i < 15; ++i) {
    int idx = tid + i * 256;          // 3840 = 60*64
    int d = idx >> 6, col = idx & 63;
    lnn[d][col] = xb[(size_t)d * N_ + n0 + col];
  }
  #pragma unroll
  for (int i = 0; i < 30; ++i) {
    int idx = tid + i * 256;          // 7680 = 60*128
    int d = idx >> 7, col = idx & 127;
    lmm[d][col] = xb[(size_t)d * N_ + m0 + col];
  }
  __syncthreads();
  int tn = tid >> 5, tm = tid & 31;   // 8 n-groups x 32 m-groups
  float acc[8][4];
  #pragma unroll
  for (int i = 0; i < 8; ++i)
    #pragma unroll
    for (int j = 0; j < 4; ++j) acc[i][j] = 0.f;
  for (int d = 0; d < D_; ++d) {
    f32x4 mv  = *(const f32x4*)&lmm[d][tm * 4];
    f32x4 nva = *(const f32x4*)&lnn[d][tn * 8];
    f32x4 nvb = *(const f32x4*)&lnn[d][tn * 8 + 4];
    #pragma unroll
    for (int i = 0; i < 4; ++i)
      #pragma unroll
      for (int j = 0; j < 4; ++j) {
        acc[i][j]     = fmaf(nva[i], mv[j], acc[i][j]);
        acc[4 + i][j] = fmaf(nvb[i], mv[j], acc[4 + i][j]);
      }
  }
  const float* xxb = xx + b * 1024;
  f32x4 xxm = *(const f32x4*)(xxb + m0 + tm * 4);
  #pragma unroll
  for (int i = 0; i < 8; ++i) {
    int n = n0 + tn * 8 + i;
    float xxn = xxb[n];
    f32x4 o;
    #pragma unroll
    for (int j = 0; j < 4; ++j) o[j] = 2.f * acc[i][j] - xxn - xxm[j];
    *(f32x4*)(pd + ((size_t)(b * 1024 + n) * 1024) + m0 + tm * 4) = o;
  }
}

// ---------------- selection: one wave per point, top-20 ----------------
__global__ __launch_bounds__(256) void k_sel(const float* __restrict__ pd,
                                             int* __restrict__ idxb) {
  int tid = threadIdx.x;
  int wave = tid >> 6, lane = tid & 63;
  int bn = blockIdx.x * 4 + wave;
  const float* row = pd + (size_t)bn * 1024;
  int mbase = lane * 16;
  f32x4 r0 = *(const f32x4*)(row + mbase);
  f32x4 r1 = *(const f32x4*)(row + mbase + 4);
  f32x4 r2 = *(const f32x4*)(row + mbase + 8);
  f32x4 r3 = *(const f32x4*)(row + mbase + 12);
  float v[16];
  #pragma unroll
  for (int j = 0; j < 4; ++j) { v[j] = r0[j]; v[4 + j] = r1[j]; v[8 + j] = r2[j]; v[12 + j] = r3[j]; }
  int* outp = idxb + (size_t)bn * K_;
  for (int kk = 0; kk < K_; ++kk) {
    float bv = v[0]; int bj = 0;
    #pragma unroll
    for (int j = 1; j < 16; ++j)
      if (v[j] > bv) { bv = v[j]; bj = j; }   // ascending: lowest j wins ties
    int bi = mbase + bj;
    #pragma unroll
    for (int off = 1; off < 64; off <<= 1) {
      float ov = __shfl_xor(bv, off);
      int   oi = __shfl_xor(bi, off);
      if (ov > bv || (ov == bv && oi < bi)) { bv = ov; bi = oi; }
    }
    if (lane == 0) outp[kk] = bi;
    #pragma unroll
    for (int j = 0; j < 16; ++j)
      if (bi == mbase + j) v[j] = -INFINITY;
  }
}

// ---------------- xt: [B][60][N] fp32 -> [P1][64] bf16 (pad 4 zeros) ----------------
__global__ __launch_bounds__(256) void k_xt(const float* __restrict__ x,
                                            short* __restrict__ xt) {
  int bn = blockIdx.x * 256 + threadIdx.x;
  int b = bn >> 10, n = bn & 1023;
  const float* xb = x + (size_t)b * D_ * N_ + n;
  short* row = xt + (size_t)bn * 64;
  for (int c = 0; c < 60; ++c) row[c] = f2b(xb[(size_t)c * N_]);
  row[60] = 0; row[61] = 0; row[62] = 0; row[63] = 0;
}

// ---------------- w1 pad: [64][120] fp32 -> [64][128] bf16 ----------------
__global__ __launch_bounds__(256) void k_w1pad(const float* __restrict__ w1,
                                               short* __restrict__ wb) {
  int t = blockIdx.x * 256 + threadIdx.x;
  int o = t >> 7, c = t & 127;
  float v = 0.f;
  if (c < 60) v = w1[o * 120 + c];
  else if (c >= 64 && c < 124) v = w1[o * 120 + 60 + (c - 64)];
  wb[t] = f2b(v);
}

// ---------------- convert w2..w6 fp32 -> bf16 ----------------
__global__ __launch_bounds__(256) void k_wcvt(const float* __restrict__ w2,
                                              const float* __restrict__ w3,
                                              const float* __restrict__ w4,
                                              const float* __restrict__ w5,
                                              const float* __restrict__ w6,
                                              short* __restrict__ wbase) {
  int t = blockIdx.x * 256 + threadIdx.x;
  if (t < 4096) wbase[WO2 + t] = f2b(w2[t]);
  else if (t < 12288) wbase[WO3 + (t - 4096)] = f2b(w3[t - 4096]);
  else if (t < 45056) wbase[WO4 + (t - 12288)] = f2b(w4[t - 12288]);
  else if (t < 176128) wbase[WO5 + (t - 45056)] = f2b(w5[t - 45056]);
  else if (t < 438272) wbase[WO6 + (t - 176128)] = f2b(w6[t - 176128]);
}

// ---------------- graph feature: [P2][128] bf16 ----------------
__global__ __launch_bounds__(256) void k_feat(const short* __restrict__ xt,
                                              const int* __restrict__ idxb,
                                              short* __restrict__ feat) {
  int t = blockIdx.x * 256 + threadIdx.x;
  int p = t >> 4, chunk = t & 15;
  int bn = p / K_;
  int nbr = (bn & ~1023) + idxb[p];
  bf16x8 o;
  if (chunk < 8) {
    bf16x8 c8 = *(const bf16x8*)(xt + (size_t)bn * 64 + chunk * 8);
    bf16x8 n8 = *(const bf16x8*)(xt + (size_t)nbr * 64 + chunk * 8);
    #pragma unroll
    for (int r = 0; r < 8; ++r) o[r] = f2b(b2f(n8[r]) - b2f(c8[r]));
  } else {
    o = *(const bf16x8*)(xt + (size_t)bn * 64 + (chunk - 8) * 8);
  }
  *(bf16x8*)(feat + (size_t)p * 128 + chunk * 8) = o;
}

// ---------------- MFMA GEMM + optional fused input-BN + fused stats ----------------
// out[P][COUT] = W[COUT][K] . act(in[P][K]) ; block 64co x 128p
template <int K, int COUT, bool APPLY, bool STATS>
__global__ __launch_bounds__(256) void k_gemm(const short* __restrict__ in,
                                              const short* __restrict__ wb,
                                              const float* __restrict__ bias,
                                              const float* __restrict__ Ain,
                                              const float* __restrict__ Bin,
                                              float* __restrict__ gsum,
                                              float* __restrict__ gssq,
                                              short* __restrict__ out, int P) {
  int tid = threadIdx.x;
  int wave = tid >> 6, lane = tid & 63;
  int ln = lane & 15, quad = lane >> 4;
  int p0 = blockIdx.x * 128 + wave * 32;
  int co0 = blockIdx.y * 64;
  f32x4 acc[4][2];
  #pragma unroll
  for (int m = 0; m < 4; ++m)
    #pragma unroll
    for (int t = 0; t < 2; ++t) acc[m][t] = (f32x4){0.f, 0.f, 0.f, 0.f};

  const short* wbase = wb + (size_t)(co0 + ln) * K + quad * 8;
  const short* ibase = in + (size_t)(p0 + ln) * K + quad * 8;
  for (int k0 = 0; k0 < K; k0 += 32) {
    bf16x8 a[4], bfr[2];
    #pragma unroll
    for (int m = 0; m < 4; ++m) a[m] = *(const bf16x8*)(wbase + (size_t)(m * 16) * K + k0);
    f32x4 pa0, pa1, pb0, pb1;
    if (APPLY) {
      pa0 = *(const f32x4*)(Ain + k0 + quad * 8);
      pa1 = *(const f32x4*)(Ain + k0 + quad * 8 + 4);
      pb0 = *(const f32x4*)(Bin + k0 + quad * 8);
      pb1 = *(const f32x4*)(Bin + k0 + quad * 8 + 4);
    }
    #pragma unroll
    for (int t = 0; t < 2; ++t) {
      bfr[t] = *(const bf16x8*)(ibase + (size_t)(t * 16) * K + k0);
      if (APPLY) {
        #pragma unroll
        for (int j = 0; j < 8; ++j) {
          float aj = j < 4 ? pa0[j] : pa1[j - 4];
          float bj = j < 4 ? pb0[j] : pb1[j - 4];
          float f = b2f(bfr[t][j]) * aj + bj;
          f = f >= 0.f ? f : 0.2f * f;
          bfr[t][j] = f2b(f);
        }
      }
    }
    #pragma unroll
    for (int m = 0; m < 4; ++m)
      #pragma unroll
      for (int t = 0; t < 2; ++t)
        acc[m][t] = __builtin_amdgcn_mfma_f32_16x16x32_bf16(a[m], bfr[t], acc[m][t], 0, 0, 0);
  }
  // add bias
  #pragma unroll
  for (int m = 0; m < 4; ++m) {
    f32x4 bs = *(const f32x4*)(bias + co0 + m * 16 + quad * 4);
    #pragma unroll
    for (int t = 0; t < 2; ++t)
      #pragma unroll
      for (int r = 0; r < 4; ++r) acc[m][t][r] += bs[r];
  }
  // store
  #pragma unroll
  for (int m = 0; m < 4; ++m)
    #pragma unroll
    for (int t = 0; t < 2; ++t) {
      int p = p0 + t * 16 + ln;
      bf16x4 o;
      #pragma unroll
      for (int r = 0; r < 4; ++r) o[r] = f2b(acc[m][t][r]);
      *(bf16x4*)(out + (size_t)p * COUT + co0 + m * 16 + quad * 4) = o;
    }
  // fused BN stats
  if (STATS) {
    __shared__ float ls[128];
    if (tid < 128) ls[tid] = 0.f;
    __syncthreads();
    #pragma unroll
    for (int m = 0; m < 4; ++m)
      #pragma unroll
      for (int r = 0; r < 4; ++r) {
        float v0 = acc[m][0][r], v1 = acc[m][1][r];
        float s = v0 + v1, ss = v0 * v0 + v1 * v1;
        #pragma unroll
        for (int off = 1; off < 16; off <<= 1) {
          s += __shfl_xor(s, off); ss += __shfl_xor(ss, off);
        }
        if (ln == 0) {
          atomicAdd(&ls[m * 16 + quad * 4 + r], s);
          atomicAdd(&ls[64 + m * 16 + quad * 4 + r], ss);
        }
      }
    __syncthreads();
    if (tid < 64) atomicAdd(&gsum[co0 + tid], ls[tid]);
    else if (tid < 128) atomicAdd(&gssq[co0 + tid - 64], ls[tid]);
  }
}

// ---------------- A = g*rsqrt(var+eps), B = be - mean*A ----------------
__global__ __launch_bounds__(256) void k_bnab(const float* __restrict__ sum,
                                              const float* __restrict__ ssq,
                                              const float* __restrict__ g,
                                              const float* __restrict__ be,
                                              float* __restrict__ A,
                                              float* __restrict__ Bp, int C, float inv) {
  int c = blockIdx.x * 256 + threadIdx.x;
  if (c < C) {
    float m = sum[c] * inv;
    float v = ssq[c] * inv - m * m;
    float a = g[c] * rsqrtf(v + 1e-5f);
    A[c] = a; Bp[c] = be[c] - m * a;
  }
}

// ---------------- BN+lrelu + max over k -> xcat (no writeback) ----------------
template <int C>
__global__ __launch_bounds__(256) void k_apply_max(const short* __restrict__ h,
                                                   const float* __restrict__ A,
                                                   const float* __restrict__ Bp,
                                                   short* __restrict__ xcat, int xoff) {
  constexpr int CH = C / 4;
  int t = blockIdx.x * 256 + threadIdx.x;  // P1*CH total
  int bn = t / CH;
  int c0 = (t % CH) * 4;
  f32x4 a = *(const f32x4*)(A + c0);
  f32x4 b = *(const f32x4*)(Bp + c0);
  float m0 = -INFINITY, m1 = -INFINITY, m2 = -INFINITY, m3 = -INFINITY;
  size_t base = (size_t)bn * K_ * C + c0;
  for (int j = 0; j < K_; ++j) {
    bf16x4 v = *(const bf16x4*)(h + base + (size_t)j * C);
    float f0 = b2f(v[0]) * a[0] + b[0]; f0 = f0 >= 0.f ? f0 : 0.2f * f0;
    float f1 = b2f(v[1]) * a[1] + b[1]; f1 = f1 >= 0.f ? f1 : 0.2f * f1;
    float f2 = b2f(v[2]) * a[2] + b[2]; f2 = f2 >= 0.f ? f2 : 0.2f * f2;
    float f3 = b2f(v[3]) * a[3] + b[3]; f3 = f3 >= 0.f ? f3 : 0.2f * f3;
    m0 = fmaxf(m0, f0); m1 = fmaxf(m1, f1); m2 = fmaxf(m2, f2); m3 = fmaxf(m3, f3);
  }
  bf16x4 o;
  o[0] = f2b(m0); o[1] = f2b(m1); o[2] = f2b(m2); o[3] = f2b(m3);
  *(bf16x4*)(xcat + (size_t)bn * 512 + xoff + c0) = o;
}

// ---------------- final: BN+lrelu bf16 [P1][1024] -> fp32 out ----------------
__global__ __launch_bounds__(256) void k_apply_out(const short* __restrict__ h,
                                                   const float* __restrict__ A,
                                                   const float* __restrict__ Bp,
                                                   float* __restrict__ out) {
  int t = blockIdx.x * 256 + threadIdx.x;
  int c0 = (t & 255) * 4;
  f32x4 a = *(const f32x4*)(A + c0);
  f32x4 b = *(const f32x4*)(Bp + c0);
  bf16x4 v = *(const bf16x4*)(h + (size_t)t * 4);
  f32x4 o;
  #pragma unroll
  for (int r = 0; r < 4; ++r) {
    float f = b2f(v[r]) * a[r] + b[r];
    o[r] = f >= 0.f ? f : 0.2f * f;
  }
  *(f32x4*)(out + (size_t)t * 4) = o;
}

extern "C" void kernel_launch(void* const* d_in, const int* in_sizes, int n_in,
                              void* d_out, int out_size, void* d_ws, size_t ws_size,
                              hipStream_t stream) {
  const float* x   = (const float*)d_in[0];
  const float* w1  = (const float*)d_in[1];
  const float* b1  = (const float*)d_in[2];
  const float* g1  = (const float*)d_in[3];
  const float* be1 = (const float*)d_in[4];
  const float* w2  = (const float*)d_in[5];
  const float* b2  = (const float*)d_in[6];
  const float* g2  = (const float*)d_in[7];
  const float* be2 = (const float*)d_in[8];
  const float* w3  = (const float*)d_in[9];
  const float* b3  = (const float*)d_in[10];
  const float* g3  = (const float*)d_in[11];
  const float* be3 = (const float*)d_in[12];
  const float* w4  = (const float*)d_in[13];
  const float* b4  = (const float*)d_in[14];
  const float* g4  = (const float*)d_in[15];
  const float* be4 = (const float*)d_in[16];
  const float* w5  = (const float*)d_in[17];
  const float* b5  = (const float*)d_in[18];
  const float* g5  = (const float*)d_in[19];
  const float* be5 = (const float*)d_in[20];
  const float* w6  = (const float*)d_in[21];
  const float* b6  = (const float*)d_in[22];
  const float* g6  = (const float*)d_in[23];
  const float* be6 = (const float*)d_in[24];
  float* out = (float*)d_out;
  char* ws = (char*)d_ws;

  int*   idxb = (int*)(ws + OFF_IDX);
  float* xx   = (float*)(ws + OFF_XX);
  float* sum  = (float*)(ws + OFF_STATS);
  float* ssq  = sum + NCH_TOT;
  float* Aall = sum + 2 * NCH_TOT;
  float* Ball = sum + 3 * NCH_TOT;
  short* xt   = (short*)(ws + OFF_XT);
  short* wbb  = (short*)(ws + OFF_WB);
  short* xcat = (short*)(ws + OFF_XC);
  short* h5   = (short*)(ws + OFF_H5);
  short* h6   = (short*)(ws + OFF_H6);
  short* feat = (short*)(ws + OFF_BIGA);
  short* h1   = (short*)(ws + OFF_H1);
  short* h2   = (short*)(ws + OFF_H2);
  short* h3   = (short*)(ws + OFF_BIGA);
  short* h4   = (short*)(ws + OFF_H4);
  float* pd   = (float*)(ws + OFF_H4);   // aliases h4; consumed before h4 written

  hipMemsetAsync(sum, 0, 2 * NCH_TOT * sizeof(float), stream);

  k_xx <<<P1_ / 256, 256, 0, stream>>>(x, xx);
  k_pd <<<dim3(8, 16, 8), 256, 0, stream>>>(x, xx, pd);
  k_sel<<<P1_ / 4, 256, 0, stream>>>(pd, idxb);
  k_xt <<<P1_ / 256, 256, 0, stream>>>(x, xt);
  k_w1pad<<<32, 256, 0, stream>>>(w1, wbb + WO1);
  k_wcvt<<<1712, 256, 0, stream>>>(w2, w3, w4, w5, w6, wbb);
  k_feat<<<P2_ * 16 / 256, 256, 0, stream>>>(xt, idxb, feat);

  // layer 1: feat[P2][128] x w1 -> h1 (raw) + stats
  k_gemm<128, 64, false, true><<<dim3(P2_ / 128, 1), 256, 0, stream>>>(
      feat, wbb + WO1, b1, nullptr, nullptr, sum + SO1, ssq + SO1, h1, P2_);
  k_bnab<<<1, 256, 0, stream>>>(sum + SO1, ssq + SO1, g1, be1, Aall + SO1, Ball + SO1, 64, 1.f / P2_);
  k_apply_max<64><<<P1_ * 16 / 256, 256, 0, stream>>>(h1, Aall + SO1, Ball + SO1, xcat, 0);

  // layer 2: act(h1) x w2 -> h2 (raw) + stats
  k_gemm<64, 64, true, true><<<dim3(P2_ / 128, 1), 256, 0, stream>>>(
      h1, wbb + WO2, b2, Aall + SO1, Ball + SO1, sum + SO2, ssq + SO2, h2, P2_);
  k_bnab<<<1, 256, 0, stream>>>(sum + SO2, ssq + SO2, g2, be2, Aall + SO2, Ball + SO2, 64, 1.f / P2_);
  k_apply_max<64><<<P1_ * 16 / 256, 256, 0, stream>>>(h2, Aall + SO2, Ball + SO2, xcat, 64);

  // layer 3: act(h2) x w3 -> h3 (raw) + stats
  k_gemm<64, 128, true, true><<<dim3(P2_ / 128, 2), 256, 0, stream>>>(
      h2, wbb + WO3, b3, Aall + SO2, Ball + SO2, sum + SO3, ssq + SO3, h3, P2_);
  k_bnab<<<1, 256, 0, stream>>>(sum + SO3, ssq + SO3, g3, be3, Aall + SO3, Ball + SO3, 128, 1.f / P2_);
  k_apply_max<128><<<P1_ * 32 / 256, 256, 0, stream>>>(h3, Aall + SO3, Ball + SO3, xcat, 128);

  // layer 4: act(h3) x w4 -> h4 (raw) + stats
  k_gemm<128, 256, true, true><<<dim3(P2_ / 128, 4), 256, 0, stream>>>(
      h3, wbb + WO4, b4, Aall + SO3, Ball + SO3, sum + SO4, ssq + SO4, h4, P2_);
  k_bnab<<<1, 256, 0, stream>>>(sum + SO4, ssq + SO4, g4, be4, Aall + SO4, Ball + SO4, 256, 1.f / P2_);
  k_apply_max<256><<<P1_ * 64 / 256, 256, 0, stream>>>(h4, Aall + SO4, Ball + SO4, xcat, 256);

  // layer 5: xcat x w5 -> h5 (raw) + stats
  k_gemm<512, 256, false, true><<<dim3(P1_ / 128, 4), 256, 0, stream>>>(
      xcat, wbb + WO5, b5, nullptr, nullptr, sum + SO5, ssq + SO5, h5, P1_);
  k_bnab<<<1, 256, 0, stream>>>(sum + SO5, ssq + SO5, g5, be5, Aall + SO5, Ball + SO5, 256, 1.f / P1_);

  // layer 6: act(h5) x w6 -> h6 (raw) + stats
  k_gemm<256, 1024, true, true><<<dim3(P1_ / 128, 16), 256, 0, stream>>>(
      h5, wbb + WO6, b6, Aall + SO5, Ball + SO5, sum + SO6, ssq + SO6, h6, P1_);
  k_bnab<<<4, 256, 0, stream>>>(sum + SO6, ssq + SO6, g6, be6, Aall + SO6, Ball + SO6, 1024, 1.f / P1_);
  k_apply_out<<<P1_ * 256 / 256, 256, 0, stream>>>(h6, Aall + SO6, Ball + SO6, out);

  (void)in_sizes; (void)n_in; (void)out_size; (void)ws_size;
}

// Round 5
// 599.149 us; speedup vs baseline: 4.1396x; 1.0139x over previous
//
#include <hip/hip_runtime.h>
#include <hip/hip_bf16.h>
#include <math.h>

#define B_ 8
#define D_ 60
#define N_ 1024
#define K_ 20
#define P1_ 8192      // B*N
#define P2_ 163840    // B*N*K

typedef __attribute__((ext_vector_type(8))) short bf16x8;
typedef __attribute__((ext_vector_type(4))) short bf16x4;
typedef __attribute__((ext_vector_type(4))) float f32x4;

__device__ inline float b2f(short s) { return __uint_as_float(((unsigned)(unsigned short)s) << 16); }
__device__ inline short f2b(float f) { __hip_bfloat16 h = __float2bfloat16(f); return *(short*)&h; }

// ---- workspace layout (bytes), all 256-aligned ----
#define OFF_IDX   0ull          // int[P2] = 655360
#define OFF_XX    655360ull     // float[P1] = 32768
#define OFF_STATS 688128ull     // sum[1792], ssq[1792], A[1792], B[1792]
#define OFF_XT    720896ull     // bf16[P1][64] = 1048576
#define OFF_WB    1769472ull    // bf16 weights
#define OFF_XC    2662400ull    // bf16[P1][512] = 8388608
#define OFF_H5    11051008ull   // bf16[P1][256] = 4194304
#define OFF_H6    15245312ull   // bf16[P1][1024] = 16777216
#define OFF_BIGA  32022528ull   // bf16[P2][128] = 41943040  (feat, later h3)
#define OFF_H1    73965568ull   // bf16[P2][64] = 20971520
#define OFF_H2    94937088ull   // bf16[P2][64] = 20971520
#define OFF_H4    115908608ull  // bf16[P2][256] = 83886080 ; pd (33.5MB) aliases here (consumed before h4 written)
// end 199794688 (~190.5 MiB)

#define WO1 0
#define WO2 8192
#define WO3 12288
#define WO4 20480
#define WO5 53248
#define WO6 184320

#define SO1 0
#define SO2 64
#define SO3 128
#define SO4 256
#define SO5 512
#define SO6 768
#define NCH_TOT 1792

// ---------------- xx[bn] = sum_d x^2 ----------------
__global__ __launch_bounds__(256) void k_xx(const float* __restrict__ x,
                                            float* __restrict__ xx) {
  int bn = blockIdx.x * 256 + threadIdx.x;
  int b = bn >> 10, n = bn & 1023;
  const float* xb = x + (size_t)b * D_ * N_ + n;
  float s = 0.f;
  for (int d = 0; d < D_; ++d) { float v = xb[(size_t)d * N_]; s += v * v; }
  xx[bn] = s;
}

// ---------------- pd[b][n][m] = 2*dot - xx_n - xx_m ; tiled fp32 ----------------
__global__ __launch_bounds__(256) void k_pd(const float* __restrict__ x,
                                            const float* __restrict__ xx,
                                            float* __restrict__ pd) {
  __shared__ float lnn[D_][64];
  __shared__ float lmm[D_][128];
  int tid = threadIdx.x;
  int m0 = blockIdx.x * 128, n0 = blockIdx.y * 64, b = blockIdx.z;
  const float* xb = x + (size_t)b * D_ * N_;
  #pragma unroll
  for (int i = 0; i < 15; ++i) {
    int idx = tid + i * 256;
    int d = idx >> 6, col = idx & 63;
    lnn[d][col] = xb[(size_t)d * N_ + n0 + col];
  }
  #pragma unroll
  for (int i = 0; i < 30; ++i) {
    int idx = tid + i * 256;
    int d = idx >> 7, col = idx & 127;
    lmm[d][col] = xb[(size_t)d * N_ + m0 + col];
  }
  __syncthreads();
  int tn = tid >> 5, tm = tid & 31;
  float acc[8][4];
  #pragma unroll
  for (int i = 0; i < 8; ++i)
    #pragma unroll
    for (int j = 0; j < 4; ++j) acc[i][j] = 0.f;
  for (int d = 0; d < D_; ++d) {
    f32x4 mv  = *(const f32x4*)&lmm[d][tm * 4];
    f32x4 nva = *(const f32x4*)&lnn[d][tn * 8];
    f32x4 nvb = *(const f32x4*)&lnn[d][tn * 8 + 4];
    #pragma unroll
    for (int i = 0; i < 4; ++i)
      #pragma unroll
      for (int j = 0; j < 4; ++j) {
        acc[i][j]     = fmaf(nva[i], mv[j], acc[i][j]);
        acc[4 + i][j] = fmaf(nvb[i], mv[j], acc[4 + i][j]);
      }
  }
  const float* xxb = xx + b * 1024;
  f32x4 xxm = *(const f32x4*)(xxb + m0 + tm * 4);
  #pragma unroll
  for (int i = 0; i < 8; ++i) {
    int n = n0 + tn * 8 + i;
    float xxn = xxb[n];
    f32x4 o;
    #pragma unroll
    for (int j = 0; j < 4; ++j) o[j] = 2.f * acc[i][j] - xxn - xxm[j];
    *(f32x4*)(pd + ((size_t)(b * 1024 + n) * 1024) + m0 + tm * 4) = o;
  }
}

// ---------------- selection: one wave per point, top-20 ----------------
__global__ __launch_bounds__(256) void k_sel(const float* __restrict__ pd,
                                             int* __restrict__ idxb) {
  int tid = threadIdx.x;
  int wave = tid >> 6, lane = tid & 63;
  int bn = blockIdx.x * 4 + wave;
  const float* row = pd + (size_t)bn * 1024;
  int mbase = lane * 16;
  f32x4 r0 = *(const f32x4*)(row + mbase);
  f32x4 r1 = *(const f32x4*)(row + mbase + 4);
  f32x4 r2 = *(const f32x4*)(row + mbase + 8);
  f32x4 r3 = *(const f32x4*)(row + mbase + 12);
  float v[16];
  #pragma unroll
  for (int j = 0; j < 4; ++j) { v[j] = r0[j]; v[4 + j] = r1[j]; v[8 + j] = r2[j]; v[12 + j] = r3[j]; }
  int* outp = idxb + (size_t)bn * K_;
  for (int kk = 0; kk < K_; ++kk) {
    float bv = v[0]; int bj = 0;
    #pragma unroll
    for (int j = 1; j < 16; ++j)
      if (v[j] > bv) { bv = v[j]; bj = j; }
    int bi = mbase + bj;
    #pragma unroll
    for (int off = 1; off < 64; off <<= 1) {
      float ov = __shfl_xor(bv, off);
      int   oi = __shfl_xor(bi, off);
      if (ov > bv || (ov == bv && oi < bi)) { bv = ov; bi = oi; }
    }
    if (lane == 0) outp[kk] = bi;
    #pragma unroll
    for (int j = 0; j < 16; ++j)
      if (bi == mbase + j) v[j] = -INFINITY;
  }
}

// ---------------- xt: [B][60][N] fp32 -> [P1][64] bf16 (pad 4 zeros) ----------------
__global__ __launch_bounds__(256) void k_xt(const float* __restrict__ x,
                                            short* __restrict__ xt) {
  int bn = blockIdx.x * 256 + threadIdx.x;
  int b = bn >> 10, n = bn & 1023;
  const float* xb = x + (size_t)b * D_ * N_ + n;
  short* row = xt + (size_t)bn * 64;
  for (int c = 0; c < 60; ++c) row[c] = f2b(xb[(size_t)c * N_]);
  row[60] = 0; row[61] = 0; row[62] = 0; row[63] = 0;
}

// ---------------- w1 pad: [64][120] fp32 -> [64][128] bf16 ----------------
__global__ __launch_bounds__(256) void k_w1pad(const float* __restrict__ w1,
                                               short* __restrict__ wb) {
  int t = blockIdx.x * 256 + threadIdx.x;
  int o = t >> 7, c = t & 127;
  float v = 0.f;
  if (c < 60) v = w1[o * 120 + c];
  else if (c >= 64 && c < 124) v = w1[o * 120 + 60 + (c - 64)];
  wb[t] = f2b(v);
}

// ---------------- convert w2..w6 fp32 -> bf16 ----------------
__global__ __launch_bounds__(256) void k_wcvt(const float* __restrict__ w2,
                                              const float* __restrict__ w3,
                                              const float* __restrict__ w4,
                                              const float* __restrict__ w5,
                                              const float* __restrict__ w6,
                                              short* __restrict__ wbase) {
  int t = blockIdx.x * 256 + threadIdx.x;
  if (t < 4096) wbase[WO2 + t] = f2b(w2[t]);
  else if (t < 12288) wbase[WO3 + (t - 4096)] = f2b(w3[t - 4096]);
  else if (t < 45056) wbase[WO4 + (t - 12288)] = f2b(w4[t - 12288]);
  else if (t < 176128) wbase[WO5 + (t - 45056)] = f2b(w5[t - 45056]);
  else if (t < 438272) wbase[WO6 + (t - 176128)] = f2b(w6[t - 176128]);
}

// ---------------- graph feature: [P2][128] bf16 ----------------
__global__ __launch_bounds__(256) void k_feat(const short* __restrict__ xt,
                                              const int* __restrict__ idxb,
                                              short* __restrict__ feat) {
  int t = blockIdx.x * 256 + threadIdx.x;
  int p = t >> 4, chunk = t & 15;
  int bn = p / K_;
  int nbr = (bn & ~1023) + idxb[p];
  bf16x8 o;
  if (chunk < 8) {
    bf16x8 c8 = *(const bf16x8*)(xt + (size_t)bn * 64 + chunk * 8);
    bf16x8 n8 = *(const bf16x8*)(xt + (size_t)nbr * 64 + chunk * 8);
    #pragma unroll
    for (int r = 0; r < 8; ++r) o[r] = f2b(b2f(n8[r]) - b2f(c8[r]));
  } else {
    o = *(const bf16x8*)(xt + (size_t)bn * 64 + (chunk - 8) * 8);
  }
  *(bf16x8*)(feat + (size_t)p * 128 + chunk * 8) = o;
}

// ---------------- LDS-staged MFMA GEMM, fused input-BN + fused stats ----------------
// out[P][COUT] = W[COUT][K] . act(in[P][K]); block p-tile 128, wave 64co x 32p.
// Input panel staged to LDS in fragment-permuted order; B-frags hoisted to regs,
// reused across co-chunks. NCO co-chunks/block (K<=128); K>128: k-panel loop.
template <int K, int COUT, int NCO, bool APPLY, bool STATS>
__global__ __launch_bounds__(256) void k_gemm(const short* __restrict__ in,
                                              const short* __restrict__ wb,
                                              const float* __restrict__ bias,
                                              const float* __restrict__ Ain,
                                              const float* __restrict__ Bin,
                                              float* __restrict__ gsum,
                                              float* __restrict__ gssq,
                                              short* __restrict__ out) {
  constexpr int PANEL = (K < 128) ? K : 128;
  constexpr int KS = PANEL / 32;        // k-steps per panel
  constexpr int CPR = PANEL / 8;        // 16B chunks per row
  constexpr int CSH = (CPR == 16) ? 4 : 3;
  constexpr int NPAN = K / PANEL;
  static_assert(NPAN == 1 || NCO == 1, "");
  __shared__ bf16x8 tile[128 * PANEL / 8];
  __shared__ float ls[128];
  int tid = threadIdx.x;
  int w = tid >> 6, lane = tid & 63;
  int ln = lane & 15, quad = lane >> 4;
  const short* src = in + (size_t)blockIdx.x * 128 * K;

  f32x4 acc[4][2];
  bf16x8 bfr[KS * 2];

  auto stage = [&](int kp) {
    #pragma unroll
    for (int i = 0; i < (128 * CPR) / 256; ++i) {
      int g = i * 256 + tid;
      int row = g >> CSH, c = g & (CPR - 1);
      bf16x8 v = *(const bf16x8*)(src + (size_t)row * K + kp + c * 8);
      if (APPLY) {
        f32x4 a0 = *(const f32x4*)(Ain + kp + c * 8);
        f32x4 a1 = *(const f32x4*)(Ain + kp + c * 8 + 4);
        f32x4 b0 = *(const f32x4*)(Bin + kp + c * 8);
        f32x4 b1 = *(const f32x4*)(Bin + kp + c * 8 + 4);
        #pragma unroll
        for (int j = 0; j < 8; ++j) {
          float aj = j < 4 ? a0[j] : a1[j - 4];
          float bj = j < 4 ? b0[j] : b1[j - 4];
          float f = b2f(v[j]) * aj + bj;
          f = f >= 0.f ? f : 0.2f * f;
          v[j] = f2b(f);
        }
      }
      int chunk = (((row >> 5) * KS + (c >> 2)) * 2 + ((row >> 4) & 1)) * 64 + (row & 15) * 4 + (c & 3);
      tile[chunk] = v;
    }
  };
  auto loadbfr = [&]() {
    #pragma unroll
    for (int ks = 0; ks < KS; ++ks)
      #pragma unroll
      for (int t = 0; t < 2; ++t)
        bfr[ks * 2 + t] = tile[((w * KS + ks) * 2 + t) * 64 + ln * 4 + quad];
  };
  auto zacc = [&]() {
    #pragma unroll
    for (int m = 0; m < 4; ++m)
      #pragma unroll
      for (int t = 0; t < 2; ++t) acc[m][t] = (f32x4){0.f, 0.f, 0.f, 0.f};
  };
  auto kloop = [&](int kp, int co0) {
    #pragma unroll
    for (int ks = 0; ks < KS; ++ks) {
      bf16x8 a[4];
      #pragma unroll
      for (int m = 0; m < 4; ++m)
        a[m] = *(const bf16x8*)(wb + (size_t)(co0 + m * 16 + ln) * K + kp + ks * 32 + quad * 8);
      #pragma unroll
      for (int m = 0; m < 4; ++m)
        #pragma unroll
        for (int t = 0; t < 2; ++t)
          acc[m][t] = __builtin_amdgcn_mfma_f32_16x16x32_bf16(a[m], bfr[ks * 2 + t], acc[m][t], 0, 0, 0);
    }
  };
  auto epilogue = [&](int co0) {
    #pragma unroll
    for (int m = 0; m < 4; ++m) {
      f32x4 bs = *(const f32x4*)(bias + co0 + m * 16 + quad * 4);
      #pragma unroll
      for (int t = 0; t < 2; ++t)
        #pragma unroll
        for (int r = 0; r < 4; ++r) acc[m][t][r] += bs[r];
    }
    #pragma unroll
    for (int m = 0; m < 4; ++m)
      #pragma unroll
      for (int t = 0; t < 2; ++t) {
        int p = blockIdx.x * 128 + w * 32 + t * 16 + ln;
        bf16x4 o;
        #pragma unroll
        for (int r = 0; r < 4; ++r) o[r] = f2b(acc[m][t][r]);
        *(bf16x4*)(out + (size_t)p * COUT + co0 + m * 16 + quad * 4) = o;
      }
    if (STATS) {
      __syncthreads();
      if (tid < 128) ls[tid] = 0.f;
      __syncthreads();
      #pragma unroll
      for (int m = 0; m < 4; ++m)
        #pragma unroll
        for (int r = 0; r < 4; ++r) {
          float v0 = acc[m][0][r], v1 = acc[m][1][r];
          float s = v0 + v1, ss = v0 * v0 + v1 * v1;
          #pragma unroll
          for (int off = 1; off < 16; off <<= 1) {
            s += __shfl_xor(s, off); ss += __shfl_xor(ss, off);
          }
          if (ln == 0) {
            atomicAdd(&ls[m * 16 + quad * 4 + r], s);
            atomicAdd(&ls[64 + m * 16 + quad * 4 + r], ss);
          }
        }
      __syncthreads();
      if (tid < 64) atomicAdd(&gsum[co0 + tid], ls[tid]);
      else if (tid < 128) atomicAdd(&gssq[co0 + tid - 64], ls[tid]);
    }
  };

  if (NPAN == 1) {
    stage(0);
    __syncthreads();
    loadbfr();
    #pragma unroll
    for (int cc = 0; cc < NCO; ++cc) {
      int co0 = (blockIdx.y * NCO + cc) * 64;
      zacc();
      kloop(0, co0);
      epilogue(co0);
    }
  } else {
    int co0 = blockIdx.y * 64;
    zacc();
    for (int pan = 0; pan < NPAN; ++pan) {
      if (pan) __syncthreads();
      stage(pan * PANEL);
      __syncthreads();
      loadbfr();
      kloop(pan * PANEL, co0);
    }
    epilogue(co0);
  }
}

// ---------------- A = g*rsqrt(var+eps), B = be - mean*A ----------------
__global__ __launch_bounds__(256) void k_bnab(const float* __restrict__ sum,
                                              const float* __restrict__ ssq,
                                              const float* __restrict__ g,
                                              const float* __restrict__ be,
                                              float* __restrict__ A,
                                              float* __restrict__ Bp, int C, float inv) {
  int c = blockIdx.x * 256 + threadIdx.x;
  if (c < C) {
    float m = sum[c] * inv;
    float v = ssq[c] * inv - m * m;
    float a = g[c] * rsqrtf(v + 1e-5f);
    A[c] = a; Bp[c] = be[c] - m * a;
  }
}

// ---------------- BN+lrelu + max over k -> xcat (no writeback) ----------------
template <int C>
__global__ __launch_bounds__(256) void k_apply_max(const short* __restrict__ h,
                                                   const float* __restrict__ A,
                                                   const float* __restrict__ Bp,
                                                   short* __restrict__ xcat, int xoff) {
  constexpr int CH = C / 4;
  int t = blockIdx.x * 256 + threadIdx.x;
  int bn = t / CH;
  int c0 = (t % CH) * 4;
  f32x4 a = *(const f32x4*)(A + c0);
  f32x4 b = *(const f32x4*)(Bp + c0);
  float m0 = -INFINITY, m1 = -INFINITY, m2 = -INFINITY, m3 = -INFINITY;
  size_t base = (size_t)bn * K_ * C + c0;
  for (int j = 0; j < K_; ++j) {
    bf16x4 v = *(const bf16x4*)(h + base + (size_t)j * C);
    float f0 = b2f(v[0]) * a[0] + b[0]; f0 = f0 >= 0.f ? f0 : 0.2f * f0;
    float f1 = b2f(v[1]) * a[1] + b[1]; f1 = f1 >= 0.f ? f1 : 0.2f * f1;
    float f2 = b2f(v[2]) * a[2] + b[2]; f2 = f2 >= 0.f ? f2 : 0.2f * f2;
    float f3 = b2f(v[3]) * a[3] + b[3]; f3 = f3 >= 0.f ? f3 : 0.2f * f3;
    m0 = fmaxf(m0, f0); m1 = fmaxf(m1, f1); m2 = fmaxf(m2, f2); m3 = fmaxf(m3, f3);
  }
  bf16x4 o;
  o[0] = f2b(m0); o[1] = f2b(m1); o[2] = f2b(m2); o[3] = f2b(m3);
  *(bf16x4*)(xcat + (size_t)bn * 512 + xoff + c0) = o;
}

// ---------------- final: BN+lrelu bf16 [P1][1024] -> fp32 out ----------------
__global__ __launch_bounds__(256) void k_apply_out(const short* __restrict__ h,
                                                   const float* __restrict__ A,
                                                   const float* __restrict__ Bp,
                                                   float* __restrict__ out) {
  int t = blockIdx.x * 256 + threadIdx.x;
  int c0 = (t & 255) * 4;
  f32x4 a = *(const f32x4*)(A + c0);
  f32x4 b = *(const f32x4*)(Bp + c0);
  bf16x4 v = *(const bf16x4*)(h + (size_t)t * 4);
  f32x4 o;
  #pragma unroll
  for (int r = 0; r < 4; ++r) {
    float f = b2f(v[r]) * a[r] + b[r];
    o[r] = f >= 0.f ? f : 0.2f * f;
  }
  *(f32x4*)(out + (size_t)t * 4) = o;
}

extern "C" void kernel_launch(void* const* d_in, const int* in_sizes, int n_in,
                              void* d_out, int out_size, void* d_ws, size_t ws_size,
                              hipStream_t stream) {
  const float* x   = (const float*)d_in[0];
  const float* w1  = (const float*)d_in[1];
  const float* b1  = (const float*)d_in[2];
  const float* g1  = (const float*)d_in[3];
  const float* be1 = (const float*)d_in[4];
  const float* w2  = (const float*)d_in[5];
  const float* b2  = (const float*)d_in[6];
  const float* g2  = (const float*)d_in[7];
  const float* be2 = (const float*)d_in[8];
  const float* w3  = (const float*)d_in[9];
  const float* b3  = (const float*)d_in[10];
  const float* g3  = (const float*)d_in[11];
  const float* be3 = (const float*)d_in[12];
  const float* w4  = (const float*)d_in[13];
  const float* b4  = (const float*)d_in[14];
  const float* g4  = (const float*)d_in[15];
  const float* be4 = (const float*)d_in[16];
  const float* w5  = (const float*)d_in[17];
  const float* b5  = (const float*)d_in[18];
  const float* g5  = (const float*)d_in[19];
  const float* be5 = (const float*)d_in[20];
  const float* w6  = (const float*)d_in[21];
  const float* b6  = (const float*)d_in[22];
  const float* g6  = (const float*)d_in[23];
  const float* be6 = (const float*)d_in[24];
  float* out = (float*)d_out;
  char* ws = (char*)d_ws;

  int*   idxb = (int*)(ws + OFF_IDX);
  float* xx   = (float*)(ws + OFF_XX);
  float* sum  = (float*)(ws + OFF_STATS);
  float* ssq  = sum + NCH_TOT;
  float* Aall = sum + 2 * NCH_TOT;
  float* Ball = sum + 3 * NCH_TOT;
  short* xt   = (short*)(ws + OFF_XT);
  short* wbb  = (short*)(ws + OFF_WB);
  short* xcat = (short*)(ws + OFF_XC);
  short* h5   = (short*)(ws + OFF_H5);
  short* h6   = (short*)(ws + OFF_H6);
  short* feat = (short*)(ws + OFF_BIGA);
  short* h1   = (short*)(ws + OFF_H1);
  short* h2   = (short*)(ws + OFF_H2);
  short* h3   = (short*)(ws + OFF_BIGA);
  short* h4   = (short*)(ws + OFF_H4);
  float* pd   = (float*)(ws + OFF_H4);   // aliases h4; consumed before h4 written

  hipMemsetAsync(sum, 0, 2 * NCH_TOT * sizeof(float), stream);

  k_xx <<<P1_ / 256, 256, 0, stream>>>(x, xx);
  k_pd <<<dim3(8, 16, 8), 256, 0, stream>>>(x, xx, pd);
  k_sel<<<P1_ / 4, 256, 0, stream>>>(pd, idxb);
  k_xt <<<P1_ / 256, 256, 0, stream>>>(x, xt);
  k_w1pad<<<32, 256, 0, stream>>>(w1, wbb + WO1);
  k_wcvt<<<1712, 256, 0, stream>>>(w2, w3, w4, w5, w6, wbb);
  k_feat<<<P2_ * 16 / 256, 256, 0, stream>>>(xt, idxb, feat);

  // layer 1: feat[P2][128] x w1 -> h1 (raw) + stats
  k_gemm<128, 64, 1, false, true><<<dim3(P2_ / 128, 1), 256, 0, stream>>>(
      feat, wbb + WO1, b1, nullptr, nullptr, sum + SO1, ssq + SO1, h1);
  k_bnab<<<1, 256, 0, stream>>>(sum + SO1, ssq + SO1, g1, be1, Aall + SO1, Ball + SO1, 64, 1.f / P2_);
  k_apply_max<64><<<P1_ * 16 / 256, 256, 0, stream>>>(h1, Aall + SO1, Ball + SO1, xcat, 0);

  // layer 2: act(h1) x w2 -> h2 (raw) + stats
  k_gemm<64, 64, 1, true, true><<<dim3(P2_ / 128, 1), 256, 0, stream>>>(
      h1, wbb + WO2, b2, Aall + SO1, Ball + SO1, sum + SO2, ssq + SO2, h2);
  k_bnab<<<1, 256, 0, stream>>>(sum + SO2, ssq + SO2, g2, be2, Aall + SO2, Ball + SO2, 64, 1.f / P2_);
  k_apply_max<64><<<P1_ * 16 / 256, 256, 0, stream>>>(h2, Aall + SO2, Ball + SO2, xcat, 64);

  // layer 3: act(h2) x w3 -> h3 (raw) + stats
  k_gemm<64, 128, 2, true, true><<<dim3(P2_ / 128, 1), 256, 0, stream>>>(
      h2, wbb + WO3, b3, Aall + SO2, Ball + SO2, sum + SO3, ssq + SO3, h3);
  k_bnab<<<1, 256, 0, stream>>>(sum + SO3, ssq + SO3, g3, be3, Aall + SO3, Ball + SO3, 128, 1.f / P2_);
  k_apply_max<128><<<P1_ * 32 / 256, 256, 0, stream>>>(h3, Aall + SO3, Ball + SO3, xcat, 128);

  // layer 4: act(h3) x w4 -> h4 (raw) + stats, all 256 co in-block
  k_gemm<128, 256, 4, true, true><<<dim3(P2_ / 128, 1), 256, 0, stream>>>(
      h3, wbb + WO4, b4, Aall + SO3, Ball + SO3, sum + SO4, ssq + SO4, h4);
  k_bnab<<<1, 256, 0, stream>>>(sum + SO4, ssq + SO4, g4, be4, Aall + SO4, Ball + SO4, 256, 1.f / P2_);
  k_apply_max<256><<<P1_ * 64 / 256, 256, 0, stream>>>(h4, Aall + SO4, Ball + SO4, xcat, 256);

  // layer 5: xcat x w5 -> h5 (raw) + stats; K=512 panels
  k_gemm<512, 256, 1, false, true><<<dim3(P1_ / 128, 4), 256, 0, stream>>>(
      xcat, wbb + WO5, b5, nullptr, nullptr, sum + SO5, ssq + SO5, h5);
  k_bnab<<<1, 256, 0, stream>>>(sum + SO5, ssq + SO5, g5, be5, Aall + SO5, Ball + SO5, 256, 1.f / P1_);

  // layer 6: act(h5) x w6 -> h6 (raw) + stats; K=256 panels
  k_gemm<256, 1024, 1, true, true><<<dim3(P1_ / 128, 16), 256, 0, stream>>>(
      h5, wbb + WO6, b6, Aall + SO5, Ball + SO5, sum + SO6, ssq + SO6, h6);
  k_bnab<<<4, 256, 0, stream>>>(sum + SO6, ssq + SO6, g6, be6, Aall + SO6, Ball + SO6, 1024, 1.f / P1_);
  k_apply_out<<<P1_ * 256 / 256, 256, 0, stream>>>(h6, Aall + SO6, Ball + SO6, out);

  (void)in_sizes; (void)n_in; (void)out_size; (void)ws_size;
}

// Round 6
// 562.712 us; speedup vs baseline: 4.4077x; 1.0648x over previous
//
#include <hip/hip_runtime.h>
#include <hip/hip_bf16.h>
#include <math.h>

#define B_ 8
#define D_ 60
#define N_ 1024
#define K_ 20
#define P1_ 8192      // B*N
#define P2_ 163840    // B*N*K

typedef __attribute__((ext_vector_type(8))) short bf16x8;
typedef __attribute__((ext_vector_type(4))) short bf16x4;
typedef __attribute__((ext_vector_type(4))) float f32x4;

__device__ inline float b2f(short s) { return __uint_as_float(((unsigned)(unsigned short)s) << 16); }
__device__ inline short f2b(float f) { __hip_bfloat16 h = __float2bfloat16(f); return *(short*)&h; }

// ---- workspace layout (bytes), all 256-aligned ----
#define OFF_IDX   0ull          // int[P2] = 655360
#define OFF_XX    655360ull     // float[P1] = 32768
#define OFF_STATS 688128ull     // sum[1792], ssq[1792], A[1792], B[1792]
#define OFF_XT    720896ull     // bf16[P1][64] = 1048576
#define OFF_WB    1769472ull    // bf16 weights
#define OFF_XC    2662400ull    // bf16[P1][512] = 8388608
#define OFF_H5    11051008ull   // bf16[P1][256] = 4194304
#define OFF_H6    15245312ull   // bf16[P1][1024] = 16777216
#define OFF_BIGA  32022528ull   // bf16[P2][128] = 41943040  (feat, later h3)
#define OFF_H1    73965568ull   // bf16[P2][64] = 20971520
#define OFF_H2    94937088ull   // bf16[P2][64] = 20971520
#define OFF_H4    115908608ull  // bf16[P2][256] = 83886080 ; pd (33.5MB) aliases here
// end 199794688 (~190.5 MiB)

#define WO1 0
#define WO2 8192
#define WO3 12288
#define WO4 20480
#define WO5 53248
#define WO6 184320

#define SO1 0
#define SO2 64
#define SO3 128
#define SO4 256
#define SO5 512
#define SO6 768
#define NCH_TOT 1792

// ---------------- xx[bn] = sum_d x^2 ----------------
__global__ __launch_bounds__(256) void k_xx(const float* __restrict__ x,
                                            float* __restrict__ xx) {
  int bn = blockIdx.x * 256 + threadIdx.x;
  int b = bn >> 10, n = bn & 1023;
  const float* xb = x + (size_t)b * D_ * N_ + n;
  float s = 0.f;
  for (int d = 0; d < D_; ++d) { float v = xb[(size_t)d * N_]; s += v * v; }
  xx[bn] = s;
}

// ---------------- pd[b][n][m] = 2*dot - xx_n - xx_m ; tiled fp32 ----------------
__global__ __launch_bounds__(256) void k_pd(const float* __restrict__ x,
                                            const float* __restrict__ xx,
                                            float* __restrict__ pd) {
  __shared__ float lnn[D_][64];
  __shared__ float lmm[D_][128];
  int tid = threadIdx.x;
  int m0 = blockIdx.x * 128, n0 = blockIdx.y * 64, b = blockIdx.z;
  const float* xb = x + (size_t)b * D_ * N_;
  #pragma unroll
  for (int i = 0; i < 15; ++i) {
    int idx = tid + i * 256;
    int d = idx >> 6, col = idx & 63;
    lnn[d][col] = xb[(size_t)d * N_ + n0 + col];
  }
  #pragma unroll
  for (int i = 0; i < 30; ++i) {
    int idx = tid + i * 256;
    int d = idx >> 7, col = idx & 127;
    lmm[d][col] = xb[(size_t)d * N_ + m0 + col];
  }
  __syncthreads();
  int tn = tid >> 5, tm = tid & 31;
  float acc[8][4];
  #pragma unroll
  for (int i = 0; i < 8; ++i)
    #pragma unroll
    for (int j = 0; j < 4; ++j) acc[i][j] = 0.f;
  for (int d = 0; d < D_; ++d) {
    f32x4 mv  = *(const f32x4*)&lmm[d][tm * 4];
    f32x4 nva = *(const f32x4*)&lnn[d][tn * 8];
    f32x4 nvb = *(const f32x4*)&lnn[d][tn * 8 + 4];
    #pragma unroll
    for (int i = 0; i < 4; ++i)
      #pragma unroll
      for (int j = 0; j < 4; ++j) {
        acc[i][j]     = fmaf(nva[i], mv[j], acc[i][j]);
        acc[4 + i][j] = fmaf(nvb[i], mv[j], acc[4 + i][j]);
      }
  }
  const float* xxb = xx + b * 1024;
  f32x4 xxm = *(const f32x4*)(xxb + m0 + tm * 4);
  #pragma unroll
  for (int i = 0; i < 8; ++i) {
    int n = n0 + tn * 8 + i;
    float xxn = xxb[n];
    f32x4 o;
    #pragma unroll
    for (int j = 0; j < 4; ++j) o[j] = 2.f * acc[i][j] - xxn - xxm[j];
    *(f32x4*)(pd + ((size_t)(b * 1024 + n) * 1024) + m0 + tm * 4) = o;
  }
}

// ---------------- selection: one wave per point, top-20 ----------------
__global__ __launch_bounds__(256) void k_sel(const float* __restrict__ pd,
                                             int* __restrict__ idxb) {
  int tid = threadIdx.x;
  int wave = tid >> 6, lane = tid & 63;
  int bn = blockIdx.x * 4 + wave;
  const float* row = pd + (size_t)bn * 1024;
  int mbase = lane * 16;
  f32x4 r0 = *(const f32x4*)(row + mbase);
  f32x4 r1 = *(const f32x4*)(row + mbase + 4);
  f32x4 r2 = *(const f32x4*)(row + mbase + 8);
  f32x4 r3 = *(const f32x4*)(row + mbase + 12);
  float v[16];
  #pragma unroll
  for (int j = 0; j < 4; ++j) { v[j] = r0[j]; v[4 + j] = r1[j]; v[8 + j] = r2[j]; v[12 + j] = r3[j]; }
  int* outp = idxb + (size_t)bn * K_;
  for (int kk = 0; kk < K_; ++kk) {
    float bv = v[0]; int bj = 0;
    #pragma unroll
    for (int j = 1; j < 16; ++j)
      if (v[j] > bv) { bv = v[j]; bj = j; }
    int bi = mbase + bj;
    #pragma unroll
    for (int off = 1; off < 64; off <<= 1) {
      float ov = __shfl_xor(bv, off);
      int   oi = __shfl_xor(bi, off);
      if (ov > bv || (ov == bv && oi < bi)) { bv = ov; bi = oi; }
    }
    if (lane == 0) outp[kk] = bi;
    #pragma unroll
    for (int j = 0; j < 16; ++j)
      if (bi == mbase + j) v[j] = -INFINITY;
  }
}

// ---------------- xt: [B][60][N] fp32 -> [P1][64] bf16 (pad 4 zeros) ----------------
__global__ __launch_bounds__(256) void k_xt(const float* __restrict__ x,
                                            short* __restrict__ xt) {
  int bn = blockIdx.x * 256 + threadIdx.x;
  int b = bn >> 10, n = bn & 1023;
  const float* xb = x + (size_t)b * D_ * N_ + n;
  short* row = xt + (size_t)bn * 64;
  for (int c = 0; c < 60; ++c) row[c] = f2b(xb[(size_t)c * N_]);
  row[60] = 0; row[61] = 0; row[62] = 0; row[63] = 0;
}

// ---------------- w1 pad: [64][120] fp32 -> [64][128] bf16 ----------------
__global__ __launch_bounds__(256) void k_w1pad(const float* __restrict__ w1,
                                               short* __restrict__ wb) {
  int t = blockIdx.x * 256 + threadIdx.x;
  int o = t >> 7, c = t & 127;
  float v = 0.f;
  if (c < 60) v = w1[o * 120 + c];
  else if (c >= 64 && c < 124) v = w1[o * 120 + 60 + (c - 64)];
  wb[t] = f2b(v);
}

// ---------------- convert w2..w6 fp32 -> bf16 ----------------
__global__ __launch_bounds__(256) void k_wcvt(const float* __restrict__ w2,
                                              const float* __restrict__ w3,
                                              const float* __restrict__ w4,
                                              const float* __restrict__ w5,
                                              const float* __restrict__ w6,
                                              short* __restrict__ wbase) {
  int t = blockIdx.x * 256 + threadIdx.x;
  if (t < 4096) wbase[WO2 + t] = f2b(w2[t]);
  else if (t < 12288) wbase[WO3 + (t - 4096)] = f2b(w3[t - 4096]);
  else if (t < 45056) wbase[WO4 + (t - 12288)] = f2b(w4[t - 12288]);
  else if (t < 176128) wbase[WO5 + (t - 45056)] = f2b(w5[t - 45056]);
  else if (t < 438272) wbase[WO6 + (t - 176128)] = f2b(w6[t - 176128]);
}

// ---------------- graph feature: [P2][128] bf16 ----------------
__global__ __launch_bounds__(256) void k_feat(const short* __restrict__ xt,
                                              const int* __restrict__ idxb,
                                              short* __restrict__ feat) {
  int t = blockIdx.x * 256 + threadIdx.x;
  int p = t >> 4, chunk = t & 15;
  int bn = p / K_;
  int nbr = (bn & ~1023) + idxb[p];
  bf16x8 o;
  if (chunk < 8) {
    bf16x8 c8 = *(const bf16x8*)(xt + (size_t)bn * 64 + chunk * 8);
    bf16x8 n8 = *(const bf16x8*)(xt + (size_t)nbr * 64 + chunk * 8);
    #pragma unroll
    for (int r = 0; r < 8; ++r) o[r] = f2b(b2f(n8[r]) - b2f(c8[r]));
  } else {
    o = *(const bf16x8*)(xt + (size_t)bn * 64 + (chunk - 8) * 8);
  }
  *(bf16x8*)(feat + (size_t)p * 128 + chunk * 8) = o;
}

// ---------------- tiled MFMA GEMM: block 128p x 64co, LDS-staged A and W ----------------
// out[P][COUT] = W[COUT][K] . act(in[P][K]) + bias, fused column stats.
// Wave: 64co x 32p (acc[4][2]).  K>128 -> k-panel loop, persistent acc.
// LDS rows padded +8 elems (16B): fragment ds_read_b128 is 2-way (free).
template <int K, int COUT, bool APPLY, bool STATS>
__global__ __launch_bounds__(256) void k_gemm(const short* __restrict__ in,
                                              const short* __restrict__ wb,
                                              const float* __restrict__ bias,
                                              const float* __restrict__ Ain,
                                              const float* __restrict__ Bin,
                                              float* __restrict__ gsum,
                                              float* __restrict__ gssq,
                                              short* __restrict__ out) {
  constexpr int PANEL = (K < 128) ? K : 128;
  constexpr int NPAN = K / PANEL;
  constexpr int CPR = PANEL / 8;            // 16B chunks per panel row
  constexpr int CSH = (CPR == 16) ? 4 : 3;
  constexpr int PK = PANEL + 8;             // padded LDS row stride (elements)
  constexpr int KS = PANEL / 32;            // MFMA k-steps per panel
  __shared__ short ldsA[128 * PK];
  __shared__ short ldsW[64 * PK];
  __shared__ float ls[128];
  int tid = threadIdx.x;
  int w = tid >> 6, lane = tid & 63;
  int ln = lane & 15, quad = lane >> 4;
  int co0 = blockIdx.y * 64;
  const short* srcA = in + (size_t)blockIdx.x * 128 * K;
  const short* srcW = wb + (size_t)co0 * K;

  f32x4 acc[4][2];
  #pragma unroll
  for (int m = 0; m < 4; ++m)
    #pragma unroll
    for (int t = 0; t < 2; ++t) acc[m][t] = (f32x4){0.f, 0.f, 0.f, 0.f};

  for (int pan = 0; pan < NPAN; ++pan) {
    int kp = pan * PANEL;
    if (pan) __syncthreads();
    // stage input panel 128 x PANEL (coalesced: 16B/lane, rows packed)
    #pragma unroll
    for (int i = 0; i < CPR / 2; ++i) {
      int g = i * 256 + tid;
      int row = g >> CSH, c = g & (CPR - 1);
      bf16x8 v = *(const bf16x8*)(srcA + (size_t)row * K + kp + c * 8);
      if (APPLY) {
        f32x4 a0 = *(const f32x4*)(Ain + kp + c * 8);
        f32x4 a1 = *(const f32x4*)(Ain + kp + c * 8 + 4);
        f32x4 b0 = *(const f32x4*)(Bin + kp + c * 8);
        f32x4 b1 = *(const f32x4*)(Bin + kp + c * 8 + 4);
        #pragma unroll
        for (int j = 0; j < 8; ++j) {
          float aj = j < 4 ? a0[j] : a1[j - 4];
          float bj = j < 4 ? b0[j] : b1[j - 4];
          float f = b2f(v[j]) * aj + bj;
          f = f >= 0.f ? f : 0.2f * f;
          v[j] = f2b(f);
        }
      }
      *(bf16x8*)(ldsA + row * PK + c * 8) = v;
    }
    // stage weight panel 64 x PANEL
    #pragma unroll
    for (int i = 0; i < CPR / 4; ++i) {
      int g = i * 256 + tid;
      int row = g >> CSH, c = g & (CPR - 1);
      *(bf16x8*)(ldsW + row * PK + c * 8) =
          *(const bf16x8*)(srcW + (size_t)row * K + kp + c * 8);
    }
    __syncthreads();
    #pragma unroll
    for (int ks = 0; ks < KS; ++ks) {
      bf16x8 a[4], bfr[2];
      #pragma unroll
      for (int m = 0; m < 4; ++m)
        a[m] = *(const bf16x8*)(ldsW + (m * 16 + ln) * PK + ks * 32 + quad * 8);
      #pragma unroll
      for (int t = 0; t < 2; ++t)
        bfr[t] = *(const bf16x8*)(ldsA + (w * 32 + t * 16 + ln) * PK + ks * 32 + quad * 8);
      #pragma unroll
      for (int m = 0; m < 4; ++m)
        #pragma unroll
        for (int t = 0; t < 2; ++t)
          acc[m][t] = __builtin_amdgcn_mfma_f32_16x16x32_bf16(a[m], bfr[t], acc[m][t], 0, 0, 0);
    }
  }
  // epilogue: bias + store
  #pragma unroll
  for (int m = 0; m < 4; ++m) {
    f32x4 bs = *(const f32x4*)(bias + co0 + m * 16 + quad * 4);
    #pragma unroll
    for (int t = 0; t < 2; ++t)
      #pragma unroll
      for (int r = 0; r < 4; ++r) acc[m][t][r] += bs[r];
  }
  #pragma unroll
  for (int m = 0; m < 4; ++m)
    #pragma unroll
    for (int t = 0; t < 2; ++t) {
      int p = blockIdx.x * 128 + w * 32 + t * 16 + ln;
      bf16x4 o;
      #pragma unroll
      for (int r = 0; r < 4; ++r) o[r] = f2b(acc[m][t][r]);
      *(bf16x4*)(out + (size_t)p * COUT + co0 + m * 16 + quad * 4) = o;
    }
  // fused BN stats (once per block)
  if (STATS) {
    __syncthreads();
    if (tid < 128) ls[tid] = 0.f;
    __syncthreads();
    #pragma unroll
    for (int m = 0; m < 4; ++m)
      #pragma unroll
      for (int r = 0; r < 4; ++r) {
        float v0 = acc[m][0][r], v1 = acc[m][1][r];
        float s = v0 + v1, ss = v0 * v0 + v1 * v1;
        #pragma unroll
        for (int off = 1; off < 16; off <<= 1) {
          s += __shfl_xor(s, off); ss += __shfl_xor(ss, off);
        }
        if (ln == 0) {
          atomicAdd(&ls[m * 16 + quad * 4 + r], s);
          atomicAdd(&ls[64 + m * 16 + quad * 4 + r], ss);
        }
      }
    __syncthreads();
    if (tid < 64) atomicAdd(&gsum[co0 + tid], ls[tid]);
    else if (tid < 128) atomicAdd(&gssq[co0 + tid - 64], ls[tid]);
  }
}

// ---------------- A = g*rsqrt(var+eps), B = be - mean*A ----------------
__global__ __launch_bounds__(256) void k_bnab(const float* __restrict__ sum,
                                              const float* __restrict__ ssq,
                                              const float* __restrict__ g,
                                              const float* __restrict__ be,
                                              float* __restrict__ A,
                                              float* __restrict__ Bp, int C, float inv) {
  int c = blockIdx.x * 256 + threadIdx.x;
  if (c < C) {
    float m = sum[c] * inv;
    float v = ssq[c] * inv - m * m;
    float a = g[c] * rsqrtf(v + 1e-5f);
    A[c] = a; Bp[c] = be[c] - m * a;
  }
}

// ---------------- BN+lrelu + max over k -> xcat (no writeback) ----------------
template <int C>
__global__ __launch_bounds__(256) void k_apply_max(const short* __restrict__ h,
                                                   const float* __restrict__ A,
                                                   const float* __restrict__ Bp,
                                                   short* __restrict__ xcat, int xoff) {
  constexpr int CH = C / 4;
  int t = blockIdx.x * 256 + threadIdx.x;
  int bn = t / CH;
  int c0 = (t % CH) * 4;
  f32x4 a = *(const f32x4*)(A + c0);
  f32x4 b = *(const f32x4*)(Bp + c0);
  float m0 = -INFINITY, m1 = -INFINITY, m2 = -INFINITY, m3 = -INFINITY;
  size_t base = (size_t)bn * K_ * C + c0;
  for (int j = 0; j < K_; ++j) {
    bf16x4 v = *(const bf16x4*)(h + base + (size_t)j * C);
    float f0 = b2f(v[0]) * a[0] + b[0]; f0 = f0 >= 0.f ? f0 : 0.2f * f0;
    float f1 = b2f(v[1]) * a[1] + b[1]; f1 = f1 >= 0.f ? f1 : 0.2f * f1;
    float f2 = b2f(v[2]) * a[2] + b[2]; f2 = f2 >= 0.f ? f2 : 0.2f * f2;
    float f3 = b2f(v[3]) * a[3] + b[3]; f3 = f3 >= 0.f ? f3 : 0.2f * f3;
    m0 = fmaxf(m0, f0); m1 = fmaxf(m1, f1); m2 = fmaxf(m2, f2); m3 = fmaxf(m3, f3);
  }
  bf16x4 o;
  o[0] = f2b(m0); o[1] = f2b(m1); o[2] = f2b(m2); o[3] = f2b(m3);
  *(bf16x4*)(xcat + (size_t)bn * 512 + xoff + c0) = o;
}

// ---------------- final: BN+lrelu bf16 [P1][1024] -> fp32 out ----------------
__global__ __launch_bounds__(256) void k_apply_out(const short* __restrict__ h,
                                                   const float* __restrict__ A,
                                                   const float* __restrict__ Bp,
                                                   float* __restrict__ out) {
  int t = blockIdx.x * 256 + threadIdx.x;
  int c0 = (t & 255) * 4;
  f32x4 a = *(const f32x4*)(A + c0);
  f32x4 b = *(const f32x4*)(Bp + c0);
  bf16x4 v = *(const bf16x4*)(h + (size_t)t * 4);
  f32x4 o;
  #pragma unroll
  for (int r = 0; r < 4; ++r) {
    float f = b2f(v[r]) * a[r] + b[r];
    o[r] = f >= 0.f ? f : 0.2f * f;
  }
  *(f32x4*)(out + (size_t)t * 4) = o;
}

extern "C" void kernel_launch(void* const* d_in, const int* in_sizes, int n_in,
                              void* d_out, int out_size, void* d_ws, size_t ws_size,
                              hipStream_t stream) {
  const float* x   = (const float*)d_in[0];
  const float* w1  = (const float*)d_in[1];
  const float* b1  = (const float*)d_in[2];
  const float* g1  = (const float*)d_in[3];
  const float* be1 = (const float*)d_in[4];
  const float* w2  = (const float*)d_in[5];
  const float* b2  = (const float*)d_in[6];
  const float* g2  = (const float*)d_in[7];
  const float* be2 = (const float*)d_in[8];
  const float* w3  = (const float*)d_in[9];
  const float* b3  = (const float*)d_in[10];
  const float* g3  = (const float*)d_in[11];
  const float* be3 = (const float*)d_in[12];
  const float* w4  = (const float*)d_in[13];
  const float* b4  = (const float*)d_in[14];
  const float* g4  = (const float*)d_in[15];
  const float* be4 = (const float*)d_in[16];
  const float* w5  = (const float*)d_in[17];
  const float* b5  = (const float*)d_in[18];
  const float* g5  = (const float*)d_in[19];
  const float* be5 = (const float*)d_in[20];
  const float* w6  = (const float*)d_in[21];
  const float* b6  = (const float*)d_in[22];
  const float* g6  = (const float*)d_in[23];
  const float* be6 = (const float*)d_in[24];
  float* out = (float*)d_out;
  char* ws = (char*)d_ws;

  int*   idxb = (int*)(ws + OFF_IDX);
  float* xx   = (float*)(ws + OFF_XX);
  float* sum  = (float*)(ws + OFF_STATS);
  float* ssq  = sum + NCH_TOT;
  float* Aall = sum + 2 * NCH_TOT;
  float* Ball = sum + 3 * NCH_TOT;
  short* xt   = (short*)(ws + OFF_XT);
  short* wbb  = (short*)(ws + OFF_WB);
  short* xcat = (short*)(ws + OFF_XC);
  short* h5   = (short*)(ws + OFF_H5);
  short* h6   = (short*)(ws + OFF_H6);
  short* feat = (short*)(ws + OFF_BIGA);
  short* h1   = (short*)(ws + OFF_H1);
  short* h2   = (short*)(ws + OFF_H2);
  short* h3   = (short*)(ws + OFF_BIGA);
  short* h4   = (short*)(ws + OFF_H4);
  float* pd   = (float*)(ws + OFF_H4);   // aliases h4; consumed before h4 written

  hipMemsetAsync(sum, 0, 2 * NCH_TOT * sizeof(float), stream);

  k_xx <<<P1_ / 256, 256, 0, stream>>>(x, xx);
  k_pd <<<dim3(8, 16, 8), 256, 0, stream>>>(x, xx, pd);
  k_sel<<<P1_ / 4, 256, 0, stream>>>(pd, idxb);
  k_xt <<<P1_ / 256, 256, 0, stream>>>(x, xt);
  k_w1pad<<<32, 256, 0, stream>>>(w1, wbb + WO1);
  k_wcvt<<<1712, 256, 0, stream>>>(w2, w3, w4, w5, w6, wbb);
  k_feat<<<P2_ * 16 / 256, 256, 0, stream>>>(xt, idxb, feat);

  // layer 1: feat[P2][128] x w1 -> h1 (raw) + stats
  k_gemm<128, 64, false, true><<<dim3(P2_ / 128, 1), 256, 0, stream>>>(
      feat, wbb + WO1, b1, nullptr, nullptr, sum + SO1, ssq + SO1, h1);
  k_bnab<<<1, 256, 0, stream>>>(sum + SO1, ssq + SO1, g1, be1, Aall + SO1, Ball + SO1, 64, 1.f / P2_);
  k_apply_max<64><<<P1_ * 16 / 256, 256, 0, stream>>>(h1, Aall + SO1, Ball + SO1, xcat, 0);

  // layer 2: act(h1) x w2 -> h2 (raw) + stats
  k_gemm<64, 64, true, true><<<dim3(P2_ / 128, 1), 256, 0, stream>>>(
      h1, wbb + WO2, b2, Aall + SO1, Ball + SO1, sum + SO2, ssq + SO2, h2);
  k_bnab<<<1, 256, 0, stream>>>(sum + SO2, ssq + SO2, g2, be2, Aall + SO2, Ball + SO2, 64, 1.f / P2_);
  k_apply_max<64><<<P1_ * 16 / 256, 256, 0, stream>>>(h2, Aall + SO2, Ball + SO2, xcat, 64);

  // layer 3: act(h2) x w3 -> h3 (raw) + stats
  k_gemm<64, 128, true, true><<<dim3(P2_ / 128, 2), 256, 0, stream>>>(
      h2, wbb + WO3, b3, Aall + SO2, Ball + SO2, sum + SO3, ssq + SO3, h3);
  k_bnab<<<1, 256, 0, stream>>>(sum + SO3, ssq + SO3, g3, be3, Aall + SO3, Ball + SO3, 128, 1.f / P2_);
  k_apply_max<128><<<P1_ * 32 / 256, 256, 0, stream>>>(h3, Aall + SO3, Ball + SO3, xcat, 128);

  // layer 4: act(h3) x w4 -> h4 (raw) + stats
  k_gemm<128, 256, true, true><<<dim3(P2_ / 128, 4), 256, 0, stream>>>(
      h3, wbb + WO4, b4, Aall + SO3, Ball + SO3, sum + SO4, ssq + SO4, h4);
  k_bnab<<<1, 256, 0, stream>>>(sum + SO4, ssq + SO4, g4, be4, Aall + SO4, Ball + SO4, 256, 1.f / P2_);
  k_apply_max<256><<<P1_ * 64 / 256, 256, 0, stream>>>(h4, Aall + SO4, Ball + SO4, xcat, 256);

  // layer 5: xcat x w5 -> h5 (raw) + stats; K=512 panels
  k_gemm<512, 256, false, true><<<dim3(P1_ / 128, 4), 256, 0, stream>>>(
      xcat, wbb + WO5, b5, nullptr, nullptr, sum + SO5, ssq + SO5, h5);
  k_bnab<<<1, 256, 0, stream>>>(sum + SO5, ssq + SO5, g5, be5, Aall + SO5, Ball + SO5, 256, 1.f / P1_);

  // layer 6: act(h5) x w6 -> h6 (raw) + stats; K=256 panels
  k_gemm<256, 1024, true, true><<<dim3(P1_ / 128, 16), 256, 0, stream>>>(
      h5, wbb + WO6, b6, Aall + SO5, Ball + SO5, sum + SO6, ssq + SO6, h6);
  k_bnab<<<4, 256, 0, stream>>>(sum + SO6, ssq + SO6, g6, be6, Aall + SO6, Ball + SO6, 1024, 1.f / P1_);
  k_apply_out<<<P1_ * 256 / 256, 256, 0, stream>>>(h6, Aall + SO6, Ball + SO6, out);

  (void)in_sizes; (void)n_in; (void)out_size; (void)ws_size;
}